// Round 5
// baseline (4652.780 us; speedup 1.0000x reference)
//
#include <hip/hip_runtime.h>
#include <cstdint>
#include <cstddef>

#define B_ 8
#define C_ 256
#define HW_ 4096
#define EPS_ 1e-5f

// ---------------- GroupNorm stats: one block per (tensor, b, g) ----------------
__global__ void gn_stats(const float* __restrict__ x, const float* __restrict__ y,
                         float* __restrict__ stats) {
  int bid = blockIdx.x;            // [0, 512)
  int which = bid >> 8;
  int b = (bid >> 5) & 7;
  int g = bid & 31;
  const float* src = which ? y : x;
  const float* base = src + ((size_t)b * C_ + (size_t)g * 8) * HW_;
  float s = 0.f, ss = 0.f;
  const float4* base4 = (const float4*)base;
  for (int i = threadIdx.x; i < 8 * HW_ / 4; i += 256) {
    float4 v = base4[i];
    s += v.x + v.y + v.z + v.w;
    ss += v.x * v.x + v.y * v.y + v.z * v.z + v.w * v.w;
  }
#pragma unroll
  for (int m = 1; m <= 32; m <<= 1) { s += __shfl_xor(s, m); ss += __shfl_xor(ss, m); }
  __shared__ float red[8];
  int wv = threadIdx.x >> 6;
  if ((threadIdx.x & 63) == 0) { red[wv] = s; red[4 + wv] = ss; }
  __syncthreads();
  if (threadIdx.x == 0) {
    float S = red[0] + red[1] + red[2] + red[3];
    float SS = red[4] + red[5] + red[6] + red[7];
    float mean = S / 32768.f;
    float var = SS / 32768.f - mean * mean;
    stats[bid * 2 + 0] = mean;
    stats[bid * 2 + 1] = rsqrtf(var + EPS_);
  }
}

// ---- fp32 GEMM: C[M][N] = A[M][256] . Bp[N][256]^T, optional GN-on-A-load ----
// AGN=1: A is a [C][HW] tensor read TRANSPOSED with GroupNorm applied:
//        A[m][k] = x[k][m]*scl[k] + off[k]   (m = pixel, k = channel)
// AGN=0: A is plain row-major [M][256].
// B is always plain row-major [N][256]. BIASM: bias indexed by m (else by n).
template<int AGN, int BIASM>
__global__ __launch_bounds__(256) void gemm32(
    const float* __restrict__ A, const float* __restrict__ Bp,
    const float* __restrict__ bias, float* __restrict__ Cout,
    const float* __restrict__ stats, const float* __restrict__ gsc,
    const float* __restrict__ gbi,
    int N, float alpha, long sA, long sB, long sC) {
  __shared__ float as[16][68];   // [k][m]
  __shared__ float bs[16][68];   // [k][n]
  int z = blockIdx.z;
  const float* Ab = A + (size_t)z * sA;
  const float* Bb = Bp + (size_t)z * sB;
  int m0 = blockIdx.x * 64, n0 = blockIdx.y * 64;
  int t = threadIdx.x;
  int tx = t & 15, ty = t >> 4;
  float acc[4][4] = {};
  for (int kk = 0; kk < 256; kk += 16) {
    __syncthreads();
    if (AGN) {
      int kidx = t >> 4, mq = (t & 15) * 4;
      int c = kk + kidx;
      float mu = stats[((size_t)z * 32 + (c >> 3)) * 2 + 0];
      float rs = stats[((size_t)z * 32 + (c >> 3)) * 2 + 1];
      float scl = rs * gsc[c];
      float off = gbi[c] - mu * scl;
      float4 v = *(const float4*)&Ab[(size_t)c * HW_ + m0 + mq];
      float4 o;
      o.x = v.x * scl + off; o.y = v.y * scl + off;
      o.z = v.z * scl + off; o.w = v.w * scl + off;
      *(float4*)&as[kidx][mq] = o;
    } else {
      int m2 = t >> 2, kq = (t & 3) * 4;
      float4 v = *(const float4*)&Ab[(size_t)(m0 + m2) * 256 + kk + kq];
      as[kq + 0][m2] = v.x; as[kq + 1][m2] = v.y;
      as[kq + 2][m2] = v.z; as[kq + 3][m2] = v.w;
    }
    {
      int n2 = t >> 2, kq = (t & 3) * 4;
      float4 w = *(const float4*)&Bb[(size_t)(n0 + n2) * 256 + kk + kq];
      bs[kq + 0][n2] = w.x; bs[kq + 1][n2] = w.y;
      bs[kq + 2][n2] = w.z; bs[kq + 3][n2] = w.w;
    }
    __syncthreads();
#pragma unroll
    for (int k = 0; k < 16; ++k) {
      float4 a4 = *(const float4*)&as[k][tx * 4];
      float4 b4 = *(const float4*)&bs[k][ty * 4];
      float av[4] = {a4.x, a4.y, a4.z, a4.w};
      float bv[4] = {b4.x, b4.y, b4.z, b4.w};
#pragma unroll
      for (int i = 0; i < 4; ++i)
#pragma unroll
        for (int j = 0; j < 4; ++j) acc[i][j] += av[i] * bv[j];
    }
  }
#pragma unroll
  for (int i = 0; i < 4; ++i) {
    int m = m0 + tx * 4 + i;
#pragma unroll
    for (int j = 0; j < 4; ++j) {
      int n = n0 + ty * 4 + j;
      float v = (acc[i][j] + bias[BIASM ? m : n]) * alpha;
      Cout[(size_t)z * sC + (size_t)m * N + n] = v;
    }
  }
}

// -------- fp32 flash attention. Q/K/V all [B][HW][C] fp32; out Ht [B][HW][C] --------
// Block: 32 q-rows, 256 threads = 32 rows x 8 channel-slices of 32.
__global__ __launch_bounds__(256) void flash32(
    const float* __restrict__ Q, const float* __restrict__ Kt,
    const float* __restrict__ Vt, float* __restrict__ Ht) {
  __shared__ float kb[16][256];   // shared K-tile then V-tile, XOR-swizzled channels
  int b = blockIdx.y, m0 = blockIdx.x * 32;
  int t = threadIdx.x, r = t >> 3, sub = t & 7;
  const float* Qb = Q + (size_t)b * HW_ * C_;
  const float* Kb = Kt + (size_t)b * HW_ * C_;
  const float* Vb = Vt + (size_t)b * HW_ * C_;
  float4 q4[8], o4[8];
  size_t qbase = (size_t)(m0 + r) * C_ + sub * 32;
#pragma unroll
  for (int j = 0; j < 8; ++j) {
    q4[j] = *(const float4*)&Qb[qbase + j * 4];
    o4[j] = (float4){0.f, 0.f, 0.f, 0.f};
  }
  float mr = -1e30f, lr = 0.f;
  int sn = t >> 4, scq = (t & 15) * 16;

  for (int n0 = 0; n0 < HW_; n0 += 16) {
    __syncthreads();
#pragma unroll
    for (int u = 0; u < 4; ++u) {
      int c = scq + u * 4;
      *(float4*)&kb[sn][c ^ ((c >> 5) << 2)] =
          *(const float4*)&Kb[(size_t)(n0 + sn) * C_ + c];
    }
    __syncthreads();
    float s[16];
#pragma unroll
    for (int n = 0; n < 16; ++n) {
      float a = 0.f;
#pragma unroll
      for (int j = 0; j < 8; ++j) {
        float4 kv = *(const float4*)&kb[n][sub * 32 + (((j ^ sub) & 7) << 2)];
        a += q4[j].x * kv.x + q4[j].y * kv.y + q4[j].z * kv.z + q4[j].w * kv.w;
      }
      a += __shfl_xor(a, 1);
      a += __shfl_xor(a, 2);
      a += __shfl_xor(a, 4);
      s[n] = a;
    }
    float tm = s[0];
#pragma unroll
    for (int n = 1; n < 16; ++n) tm = fmaxf(tm, s[n]);
    float mn = fmaxf(mr, tm);
    float corr = __expf(mr - mn);
    mr = mn;
    float p[16];
    float su = 0.f;
#pragma unroll
    for (int n = 0; n < 16; ++n) { p[n] = __expf(s[n] - mn); su += p[n]; }
    lr = lr * corr + su;
#pragma unroll
    for (int j = 0; j < 8; ++j) {
      o4[j].x *= corr; o4[j].y *= corr; o4[j].z *= corr; o4[j].w *= corr;
    }
    __syncthreads();
#pragma unroll
    for (int u = 0; u < 4; ++u) {
      int c = scq + u * 4;
      *(float4*)&kb[sn][c ^ ((c >> 5) << 2)] =
          *(const float4*)&Vb[(size_t)(n0 + sn) * C_ + c];
    }
    __syncthreads();
#pragma unroll
    for (int n = 0; n < 16; ++n) {
#pragma unroll
      for (int j = 0; j < 8; ++j) {
        float4 vv = *(const float4*)&kb[n][sub * 32 + (((j ^ sub) & 7) << 2)];
        o4[j].x += p[n] * vv.x; o4[j].y += p[n] * vv.y;
        o4[j].z += p[n] * vv.z; o4[j].w += p[n] * vv.w;
      }
    }
  }
  float inv = 1.f / lr;
  size_t hbase = (size_t)b * HW_ * C_ + qbase;
#pragma unroll
  for (int j = 0; j < 8; ++j) {
    float4 v = o4[j];
    v.x *= inv; v.y *= inv; v.z *= inv; v.w *= inv;
    *(float4*)&Ht[hbase + j * 4] = v;
  }
}

extern "C" void kernel_launch(void* const* d_in, const int* in_sizes, int n_in,
                              void* d_out, int out_size, void* d_ws, size_t ws_size,
                              hipStream_t stream) {
  const float* x   = (const float*)d_in[0];
  const float* tg  = (const float*)d_in[1];
  const float* gsc = (const float*)d_in[2];
  const float* gbi = (const float*)d_in[3];
  const float* Wq  = (const float*)d_in[4];
  const float* bq  = (const float*)d_in[5];
  const float* Wk  = (const float*)d_in[6];
  const float* bk  = (const float*)d_in[7];
  const float* Wv  = (const float*)d_in[8];
  const float* bv  = (const float*)d_in[9];
  const float* Wp  = (const float*)d_in[10];
  const float* bp  = (const float*)d_in[11];

  char* ws = (char*)d_ws;
  size_t off = 0;
  auto alloc = [&](size_t bytes) {
    char* p = ws + off;
    off += (bytes + 255) & ~(size_t)255;
    return p;
  };
  const size_t TSZ = (size_t)B_ * HW_ * C_ * sizeof(float);  // 33.55 MB
  float* qt = (float*)alloc(TSZ);
  float* kt = (float*)alloc(TSZ);
  float* vt = (float*)alloc(TSZ);
  float* stats = (float*)alloc((size_t)2 * B_ * 32 * 2 * sizeof(float));
  // ht overlays qt: flash32 hoists its q rows to registers before writing ht,
  // and each block only writes the rows it read.
  float* ht = qt;

  gn_stats<<<dim3(512), dim3(256), 0, stream>>>(x, tg, stats);

  const long sIn = (long)C_ * HW_;   // x/tg per-batch stride
  const long sT  = (long)HW_ * C_;   // qt/kt/vt/ht per-batch stride

  // q[b][n][o] = (GN(x)[n][:] . Wq[o][:] + bq[o]) * C^-0.5
  gemm32<1, 0><<<dim3(64, 4, 8), dim3(256), 0, stream>>>(
      x, Wq, bq, qt, stats, gsc, gbi, C_, 0.0625f, sIn, 0L, sT);
  // k[b][n][o] = GN(tg)[n][:] . Wk[o][:] + bk[o]
  gemm32<1, 0><<<dim3(64, 4, 8), dim3(256), 0, stream>>>(
      tg, Wk, bk, kt, stats + 512, gsc, gbi, C_, 1.f, sIn, 0L, sT);
  // v[b][n][o] = GN(tg)[n][:] . Wv[o][:] + bv[o]
  gemm32<1, 0><<<dim3(64, 4, 8), dim3(256), 0, stream>>>(
      tg, Wv, bv, vt, stats + 512, gsc, gbi, C_, 1.f, sIn, 0L, sT);
  // attention (all fp32)
  flash32<<<dim3(128, 8), dim3(256), 0, stream>>>(qt, kt, vt, ht);
  // out[b][o][n] = Wp[o][:] . h[n][:] + bp[o]
  gemm32<0, 1><<<dim3(4, 64, 8), dim3(256), 0, stream>>>(
      Wp, ht, bp, (float*)d_out, nullptr, nullptr, nullptr,
      HW_, 1.f, 0L, sT, (long)C_ * HW_);
}

// Round 6
// 1101.477 us; speedup vs baseline: 4.2241x; 4.2241x over previous
//
#include <hip/hip_runtime.h>
#include <cstdint>
#include <cstddef>

typedef _Float16 f16;
typedef _Float16 half8 __attribute__((ext_vector_type(8)));
typedef float floatx4 __attribute__((ext_vector_type(4)));

#define B_ 8
#define C_ 256
#define HW_ 4096
#define EPS_ 1e-5f
#define LO_S 2048.0f          // lo parts stored pre-scaled by 2^11 (keeps them fp16-normal)
#define LO_I (1.0f / 2048.0f)

__device__ __forceinline__ floatx4 mfma16(half8 a, half8 b, floatx4 c) {
  return __builtin_amdgcn_mfma_f32_16x16x32_f16(a, b, c, 0, 0, 0);
}

// ---------------- GroupNorm stats: one block per (tensor, b, g) ----------------
__global__ void gn_stats(const float* __restrict__ x, const float* __restrict__ y,
                         float* __restrict__ stats) {
  int bid = blockIdx.x;            // [0, 512)
  int which = bid >> 8;
  int b = (bid >> 5) & 7;
  int g = bid & 31;
  const float* src = which ? y : x;
  const float* base = src + ((size_t)b * C_ + (size_t)g * 8) * HW_;
  float s = 0.f, ss = 0.f;
  const float4* base4 = (const float4*)base;
  for (int i = threadIdx.x; i < 8 * HW_ / 4; i += 256) {
    float4 v = base4[i];
    s += v.x + v.y + v.z + v.w;
    ss += v.x * v.x + v.y * v.y + v.z * v.z + v.w * v.w;
  }
#pragma unroll
  for (int m = 1; m <= 32; m <<= 1) { s += __shfl_xor(s, m); ss += __shfl_xor(ss, m); }
  __shared__ float red[8];
  int wv = threadIdx.x >> 6;
  if ((threadIdx.x & 63) == 0) { red[wv] = s; red[4 + wv] = ss; }
  __syncthreads();
  if (threadIdx.x == 0) {
    float S = red[0] + red[1] + red[2] + red[3];
    float SS = red[4] + red[5] + red[6] + red[7];
    float mean = S / 32768.f;
    float var = SS / 32768.f - mean * mean;
    stats[bid * 2 + 0] = mean;
    stats[bid * 2 + 1] = rsqrtf(var + EPS_);
  }
}

// ---- fp32 GEMM: C[M][N] = (A[M][256] . Bp[N][256]^T + bias) * alpha ----
// AGN/BGN=1: that operand comes from a [C][HW] fp32 tensor, read transposed with
// GroupNorm fused (operand[i][k] = t[k][i]*scl[k]+off[k]).
// OUT=0: fp32 single to Ch.  OUT=1: split fp16 pair (hi -> Ch, (v-hi)*2048 -> Cl).
template<int AGN, int BGN, int BIASM, int OUT>
__global__ __launch_bounds__(256) void gemm32(
    const float* __restrict__ A, const float* __restrict__ Bp,
    const float* __restrict__ bias,
    void* __restrict__ Ch, void* __restrict__ Cl,
    const float* __restrict__ stats, const float* __restrict__ gsc,
    const float* __restrict__ gbi,
    int N, float alpha, long sA, long sB, long sC) {
  __shared__ float as[16][68];   // [k][m]
  __shared__ float bs[16][68];   // [k][n]
  int z = blockIdx.z;
  const float* Ab = A + (size_t)z * sA;
  const float* Bb = Bp + (size_t)z * sB;
  int m0 = blockIdx.x * 64, n0 = blockIdx.y * 64;
  int t = threadIdx.x;
  int tx = t & 15, ty = t >> 4;
  float acc[4][4] = {};
  for (int kk = 0; kk < 256; kk += 16) {
    __syncthreads();
    if (AGN) {
      int kidx = t >> 4, mq = (t & 15) * 4;
      int c = kk + kidx;
      float mu = stats[((size_t)z * 32 + (c >> 3)) * 2 + 0];
      float rs = stats[((size_t)z * 32 + (c >> 3)) * 2 + 1];
      float scl = rs * gsc[c];
      float off = gbi[c] - mu * scl;
      float4 v = *(const float4*)&Ab[(size_t)c * HW_ + m0 + mq];
      float4 o;
      o.x = v.x * scl + off; o.y = v.y * scl + off;
      o.z = v.z * scl + off; o.w = v.w * scl + off;
      *(float4*)&as[kidx][mq] = o;
    } else {
      int m2 = t >> 2, kq = (t & 3) * 4;
      float4 v = *(const float4*)&Ab[(size_t)(m0 + m2) * 256 + kk + kq];
      as[kq + 0][m2] = v.x; as[kq + 1][m2] = v.y;
      as[kq + 2][m2] = v.z; as[kq + 3][m2] = v.w;
    }
    if (BGN) {
      int kidx = t >> 4, nq = (t & 15) * 4;
      int c = kk + kidx;
      float mu = stats[((size_t)z * 32 + (c >> 3)) * 2 + 0];
      float rs = stats[((size_t)z * 32 + (c >> 3)) * 2 + 1];
      float scl = rs * gsc[c];
      float off = gbi[c] - mu * scl;
      float4 v = *(const float4*)&Bb[(size_t)c * HW_ + n0 + nq];
      float4 o;
      o.x = v.x * scl + off; o.y = v.y * scl + off;
      o.z = v.z * scl + off; o.w = v.w * scl + off;
      *(float4*)&bs[kidx][nq] = o;
    } else {
      int n2 = t >> 2, kq = (t & 3) * 4;
      float4 w = *(const float4*)&Bb[(size_t)(n0 + n2) * 256 + kk + kq];
      bs[kq + 0][n2] = w.x; bs[kq + 1][n2] = w.y;
      bs[kq + 2][n2] = w.z; bs[kq + 3][n2] = w.w;
    }
    __syncthreads();
#pragma unroll
    for (int k = 0; k < 16; ++k) {
      float4 a4 = *(const float4*)&as[k][tx * 4];
      float4 b4 = *(const float4*)&bs[k][ty * 4];
      float av[4] = {a4.x, a4.y, a4.z, a4.w};
      float bv[4] = {b4.x, b4.y, b4.z, b4.w};
#pragma unroll
      for (int i = 0; i < 4; ++i)
#pragma unroll
        for (int j = 0; j < 4; ++j) acc[i][j] += av[i] * bv[j];
    }
  }
#pragma unroll
  for (int i = 0; i < 4; ++i) {
    int m = m0 + tx * 4 + i;
#pragma unroll
    for (int j = 0; j < 4; ++j) {
      int n = n0 + ty * 4 + j;
      float v = (acc[i][j] + bias[BIASM ? m : n]) * alpha;
      size_t idx = (size_t)z * sC + (size_t)m * N + n;
      if (OUT == 0) {
        ((float*)Ch)[idx] = v;
      } else {
        f16 hi = (f16)v;
        ((f16*)Ch)[idx] = hi;
        ((f16*)Cl)[idx] = (f16)((v - (float)hi) * LO_S);
      }
    }
  }
}

// aligned-8B half8 load (for 72B-stride V rows)
__device__ __forceinline__ half8 ld8u2(const f16* p) {
  union { half8 h; uint2 u[2]; } t;
  t.u[0] = *(const uint2*)p;
  t.u[1] = *(const uint2*)(p + 4);
  return t.h;
}

// -------- split-fp16 MFMA flash attention (numerically ~fp32) --------
// Qh/Ql,Kh/Kl: [B][HW][C] f16 (lo pre-scaled x2048); Vh/Vl: [B][C][HW] f16.
// Out Ht: [B][HW][C] fp32.
__global__ __launch_bounds__(256, 2) void flashsp(
    const f16* __restrict__ Qh, const f16* __restrict__ Ql,
    const f16* __restrict__ Kh, const f16* __restrict__ Kl,
    const f16* __restrict__ Vh, const f16* __restrict__ Vl,
    float* __restrict__ Ht) {
  int b = blockIdx.y;
  int m0 = blockIdx.x * 64;
  int lane = threadIdx.x & 63;
  int wv = threadIdx.x >> 6;
  int l15 = lane & 15;
  int koff = (lane >> 4) * 8;
  const f16* Qbh = Qh + (size_t)b * HW_ * C_;
  const f16* Qbl = Ql + (size_t)b * HW_ * C_;
  const f16* Kbh = Kh + (size_t)b * HW_ * C_;
  const f16* Kbl = Kl + (size_t)b * HW_ * C_;
  const f16* Vbh = Vh + (size_t)b * C_ * HW_;
  const f16* Vbl = Vl + (size_t)b * C_ * HW_;

  __shared__ f16 ksh[32][264], ksl[32][264];   // 528B rows, 16B-aligned
  __shared__ f16 vsh[256][36], vsl[256][36];   // 72B rows, 8B-aligned (uint2 access)
  __shared__ f16 psh[4][16][40], psl[4][16][40];

  int mrow = m0 + wv * 16 + l15;
  half8 qfh[8], qfl[8];
#pragma unroll
  for (int kk = 0; kk < 8; ++kk) {
    qfh[kk] = *(const half8*)(Qbh + (size_t)mrow * C_ + kk * 32 + koff);
    qfl[kk] = *(const half8*)(Qbl + (size_t)mrow * C_ + kk * 32 + koff);
  }

  floatx4 o[16];
#pragma unroll
  for (int i = 0; i < 16; ++i) o[i] = (floatx4){0.f, 0.f, 0.f, 0.f};
  float m_run[4] = {-1e30f, -1e30f, -1e30f, -1e30f};
  float l_run[4] = {0.f, 0.f, 0.f, 0.f};

  int krow = threadIdx.x >> 3;
  int kch = (threadIdx.x & 7) * 32;

  for (int n0 = 0; n0 < HW_; n0 += 32) {
    __syncthreads();
    {
      const uint4* sh = (const uint4*)(Kbh + (size_t)(n0 + krow) * C_ + kch);
      const uint4* sl = (const uint4*)(Kbl + (size_t)(n0 + krow) * C_ + kch);
      uint4* dh = (uint4*)&ksh[krow][kch];
      uint4* dl = (uint4*)&ksl[krow][kch];
      dh[0] = sh[0]; dh[1] = sh[1]; dh[2] = sh[2]; dh[3] = sh[3];
      dl[0] = sl[0]; dl[1] = sl[1]; dl[2] = sl[2]; dl[3] = sl[3];
      const uint4* svh = (const uint4*)(Vbh + (size_t)threadIdx.x * HW_ + n0);
      const uint4* svl = (const uint4*)(Vbl + (size_t)threadIdx.x * HW_ + n0);
#pragma unroll
      for (int u = 0; u < 4; ++u) {
        uint4 a = svh[u], c = svl[u];
        *(uint2*)&vsh[threadIdx.x][u * 8]     = make_uint2(a.x, a.y);
        *(uint2*)&vsh[threadIdx.x][u * 8 + 4] = make_uint2(a.z, a.w);
        *(uint2*)&vsl[threadIdx.x][u * 8]     = make_uint2(c.x, c.y);
        *(uint2*)&vsl[threadIdx.x][u * 8 + 4] = make_uint2(c.z, c.w);
      }
    }
    __syncthreads();

    floatx4 s0h = {0.f,0.f,0.f,0.f}, s0x = {0.f,0.f,0.f,0.f};
    floatx4 s1h = {0.f,0.f,0.f,0.f}, s1x = {0.f,0.f,0.f,0.f};
#pragma unroll
    for (int kk = 0; kk < 8; ++kk) {
      half8 k0h = *(const half8*)&ksh[l15][kk * 32 + koff];
      half8 k0l = *(const half8*)&ksl[l15][kk * 32 + koff];
      half8 k1h = *(const half8*)&ksh[16 + l15][kk * 32 + koff];
      half8 k1l = *(const half8*)&ksl[16 + l15][kk * 32 + koff];
      s0h = mfma16(qfh[kk], k0h, s0h);
      s0x = mfma16(qfh[kk], k0l, s0x);
      s0x = mfma16(qfl[kk], k0h, s0x);
      s1h = mfma16(qfh[kk], k1h, s1h);
      s1x = mfma16(qfh[kk], k1l, s1x);
      s1x = mfma16(qfl[kk], k1h, s1x);
    }
    float p0[4], p1[4], sc[4];
#pragma unroll
    for (int r = 0; r < 4; ++r) {
      float v0 = s0h[r] + s0x[r] * LO_I;
      float v1 = s1h[r] + s1x[r] * LO_I;
      float t = fmaxf(v0, v1);
      t = fmaxf(t, __shfl_xor(t, 1));
      t = fmaxf(t, __shfl_xor(t, 2));
      t = fmaxf(t, __shfl_xor(t, 4));
      t = fmaxf(t, __shfl_xor(t, 8));
      float mn = fmaxf(m_run[r], t);
      sc[r] = __expf(m_run[r] - mn);
      m_run[r] = mn;
      p0[r] = __expf(v0 - mn);
      p1[r] = __expf(v1 - mn);
      float su = p0[r] + p1[r];
      su += __shfl_xor(su, 1);
      su += __shfl_xor(su, 2);
      su += __shfl_xor(su, 4);
      su += __shfl_xor(su, 8);
      l_run[r] = l_run[r] * sc[r] + su;
    }
#pragma unroll
    for (int i = 0; i < 16; ++i) {
      o[i][0] *= sc[0]; o[i][1] *= sc[1]; o[i][2] *= sc[2]; o[i][3] *= sc[3];
    }
#pragma unroll
    for (int r = 0; r < 4; ++r) {
      int mr = (lane >> 4) * 4 + r;
      f16 h0 = (f16)p0[r], h1 = (f16)p1[r];
      psh[wv][mr][l15] = h0;
      psh[wv][mr][16 + l15] = h1;
      psl[wv][mr][l15] = (f16)((p0[r] - (float)h0) * LO_S);
      psl[wv][mr][16 + l15] = (f16)((p1[r] - (float)h1) * LO_S);
    }
    asm volatile("s_waitcnt lgkmcnt(0)" ::: "memory");
    __builtin_amdgcn_sched_barrier(0);
    half8 pfh = *(const half8*)&psh[wv][l15][koff];
    half8 pfl = *(const half8*)&psl[wv][l15][koff];
#pragma unroll
    for (int ct = 0; ct < 16; ++ct) {
      half8 vfh = ld8u2(&vsh[ct * 16 + l15][koff]);
      half8 vfl = ld8u2(&vsl[ct * 16 + l15][koff]);
      floatx4 om = {0.f, 0.f, 0.f, 0.f};
      om = mfma16(pfh, vfl, om);
      om = mfma16(pfl, vfh, om);
      o[ct] = mfma16(pfh, vfh, o[ct]);
      o[ct][0] += om[0] * LO_I; o[ct][1] += om[1] * LO_I;
      o[ct][2] += om[2] * LO_I; o[ct][3] += om[3] * LO_I;
    }
  }

  float inv[4];
#pragma unroll
  for (int r = 0; r < 4; ++r) inv[r] = 1.f / l_run[r];
#pragma unroll
  for (int ct = 0; ct < 16; ++ct) {
#pragma unroll
    for (int r = 0; r < 4; ++r) {
      int m = m0 + wv * 16 + (lane >> 4) * 4 + r;
      Ht[((size_t)b * HW_ + m) * C_ + ct * 16 + l15] = o[ct][r] * inv[r];
    }
  }
}

extern "C" void kernel_launch(void* const* d_in, const int* in_sizes, int n_in,
                              void* d_out, int out_size, void* d_ws, size_t ws_size,
                              hipStream_t stream) {
  const float* x   = (const float*)d_in[0];
  const float* tg  = (const float*)d_in[1];
  const float* gsc = (const float*)d_in[2];
  const float* gbi = (const float*)d_in[3];
  const float* Wq  = (const float*)d_in[4];
  const float* bq  = (const float*)d_in[5];
  const float* Wk  = (const float*)d_in[6];
  const float* bk  = (const float*)d_in[7];
  const float* Wv  = (const float*)d_in[8];
  const float* bv  = (const float*)d_in[9];
  const float* Wp  = (const float*)d_in[10];
  const float* bp  = (const float*)d_in[11];

  char* ws = (char*)d_ws;
  size_t off = 0;
  auto alloc = [&](size_t bytes) {
    char* p = ws + off;
    off += (bytes + 255) & ~(size_t)255;
    return p;
  };
  const size_t HSZ = (size_t)B_ * HW_ * C_ * sizeof(f16);   // 16.78 MB
  f16* qh = (f16*)alloc(HSZ);
  f16* ql = (f16*)alloc(HSZ);
  f16* kh = (f16*)alloc(HSZ);
  f16* kl = (f16*)alloc(HSZ);
  f16* vh = (f16*)alloc(HSZ);
  f16* vl = (f16*)alloc(HSZ);
  float* ht = (float*)alloc((size_t)B_ * HW_ * C_ * sizeof(float));  // 33.55 MB
  float* stats = (float*)alloc((size_t)2 * B_ * 32 * 2 * sizeof(float));

  gn_stats<<<dim3(512), dim3(256), 0, stream>>>(x, tg, stats);

  const long sIn = (long)C_ * HW_;
  const long sT  = (long)HW_ * C_;

  // q = (GN(x).Wq^T + bq)*C^-0.5 -> split f16 [B][HW][C]
  gemm32<1, 0, 0, 1><<<dim3(64, 4, 8), dim3(256), 0, stream>>>(
      x, Wq, bq, qh, ql, stats, gsc, gbi, C_, 0.0625f, sIn, 0L, sT);
  // k = GN(tg).Wk^T + bk -> split f16 [B][HW][C]
  gemm32<1, 0, 0, 1><<<dim3(64, 4, 8), dim3(256), 0, stream>>>(
      tg, Wk, bk, kh, kl, stats + 512, gsc, gbi, C_, 1.f, sIn, 0L, sT);
  // vT = Wv.GN(tg)^T + bv -> split f16 [B][C][HW]
  gemm32<0, 1, 1, 1><<<dim3(4, 64, 8), dim3(256), 0, stream>>>(
      Wv, tg, bv, vh, vl, stats + 512, gsc, gbi, HW_, 1.f, 0L, sIn, sT);
  // attention (split-fp16 MFMA, fp32-equivalent)
  flashsp<<<dim3(64, 8), dim3(256), 0, stream>>>(qh, ql, kh, kl, vh, vl, ht);
  // out = Wp.h^T + bp -> [B][C][HW] fp32
  gemm32<0, 0, 1, 0><<<dim3(4, 64, 8), dim3(256), 0, stream>>>(
      Wp, ht, bp, d_out, nullptr, nullptr, nullptr, nullptr,
      HW_, 1.f, 0L, sT, (long)C_ * HW_);
}

// Round 7
// 1091.684 us; speedup vs baseline: 4.2620x; 1.0090x over previous
//
#include <hip/hip_runtime.h>
#include <cstdint>
#include <cstddef>

typedef _Float16 f16;
typedef _Float16 half8 __attribute__((ext_vector_type(8)));
typedef float floatx4 __attribute__((ext_vector_type(4)));

#define B_ 8
#define C_ 256
#define HW_ 4096
#define EPS_ 1e-5f
#define LO_S 2048.0f          // lo parts stored pre-scaled by 2^11 (keeps them fp16-normal)
#define LO_I (1.0f / 2048.0f)
#define KVB 32
#define DEFER_THR 8.0f        // T13: skip O-rescale while tile max <= m_run + THR

__device__ __forceinline__ floatx4 mfma16(half8 a, half8 b, floatx4 c) {
  return __builtin_amdgcn_mfma_f32_16x16x32_f16(a, b, c, 0, 0, 0);
}

// ---------------- GroupNorm stats: one block per (tensor, b, g) ----------------
__global__ void gn_stats(const float* __restrict__ x, const float* __restrict__ y,
                         float* __restrict__ stats) {
  int bid = blockIdx.x;            // [0, 512)
  int which = bid >> 8;
  int b = (bid >> 5) & 7;
  int g = bid & 31;
  const float* src = which ? y : x;
  const float* base = src + ((size_t)b * C_ + (size_t)g * 8) * HW_;
  float s = 0.f, ss = 0.f;
  const float4* base4 = (const float4*)base;
  for (int i = threadIdx.x; i < 8 * HW_ / 4; i += 256) {
    float4 v = base4[i];
    s += v.x + v.y + v.z + v.w;
    ss += v.x * v.x + v.y * v.y + v.z * v.z + v.w * v.w;
  }
#pragma unroll
  for (int m = 1; m <= 32; m <<= 1) { s += __shfl_xor(s, m); ss += __shfl_xor(ss, m); }
  __shared__ float red[8];
  int wv = threadIdx.x >> 6;
  if ((threadIdx.x & 63) == 0) { red[wv] = s; red[4 + wv] = ss; }
  __syncthreads();
  if (threadIdx.x == 0) {
    float S = red[0] + red[1] + red[2] + red[3];
    float SS = red[4] + red[5] + red[6] + red[7];
    float mean = S / 32768.f;
    float var = SS / 32768.f - mean * mean;
    stats[bid * 2 + 0] = mean;
    stats[bid * 2 + 1] = rsqrtf(var + EPS_);
  }
}

// ---- fp32 GEMM: C[M][N] = (A[M][256] . Bp[N][256]^T + bias) * alpha ----
// AGN/BGN=1: operand from [C][HW] fp32 tensor, transposed + GroupNorm fused.
// OUT=0: fp32 to Ch.  OUT=1: split fp16 (hi -> Ch, (v-hi)*2048 -> Cl).
template<int AGN, int BGN, int BIASM, int OUT>
__global__ __launch_bounds__(256) void gemm32(
    const float* __restrict__ A, const float* __restrict__ Bp,
    const float* __restrict__ bias,
    void* __restrict__ Ch, void* __restrict__ Cl,
    const float* __restrict__ stats, const float* __restrict__ gsc,
    const float* __restrict__ gbi,
    int N, float alpha, long sA, long sB, long sC) {
  __shared__ float as[16][68];   // [k][m]
  __shared__ float bs[16][68];   // [k][n]
  int z = blockIdx.z;
  const float* Ab = A + (size_t)z * sA;
  const float* Bb = Bp + (size_t)z * sB;
  int m0 = blockIdx.x * 64, n0 = blockIdx.y * 64;
  int t = threadIdx.x;
  int tx = t & 15, ty = t >> 4;
  float acc[4][4] = {};
  for (int kk = 0; kk < 256; kk += 16) {
    __syncthreads();
    if (AGN) {
      int kidx = t >> 4, mq = (t & 15) * 4;
      int c = kk + kidx;
      float mu = stats[((size_t)z * 32 + (c >> 3)) * 2 + 0];
      float rs = stats[((size_t)z * 32 + (c >> 3)) * 2 + 1];
      float scl = rs * gsc[c];
      float off = gbi[c] - mu * scl;
      float4 v = *(const float4*)&Ab[(size_t)c * HW_ + m0 + mq];
      float4 o;
      o.x = v.x * scl + off; o.y = v.y * scl + off;
      o.z = v.z * scl + off; o.w = v.w * scl + off;
      *(float4*)&as[kidx][mq] = o;
    } else {
      int m2 = t >> 2, kq = (t & 3) * 4;
      float4 v = *(const float4*)&Ab[(size_t)(m0 + m2) * 256 + kk + kq];
      as[kq + 0][m2] = v.x; as[kq + 1][m2] = v.y;
      as[kq + 2][m2] = v.z; as[kq + 3][m2] = v.w;
    }
    if (BGN) {
      int kidx = t >> 4, nq = (t & 15) * 4;
      int c = kk + kidx;
      float mu = stats[((size_t)z * 32 + (c >> 3)) * 2 + 0];
      float rs = stats[((size_t)z * 32 + (c >> 3)) * 2 + 1];
      float scl = rs * gsc[c];
      float off = gbi[c] - mu * scl;
      float4 v = *(const float4*)&Bb[(size_t)c * HW_ + n0 + nq];
      float4 o;
      o.x = v.x * scl + off; o.y = v.y * scl + off;
      o.z = v.z * scl + off; o.w = v.w * scl + off;
      *(float4*)&bs[kidx][nq] = o;
    } else {
      int n2 = t >> 2, kq = (t & 3) * 4;
      float4 w = *(const float4*)&Bb[(size_t)(n0 + n2) * 256 + kk + kq];
      bs[kq + 0][n2] = w.x; bs[kq + 1][n2] = w.y;
      bs[kq + 2][n2] = w.z; bs[kq + 3][n2] = w.w;
    }
    __syncthreads();
#pragma unroll
    for (int k = 0; k < 16; ++k) {
      float4 a4 = *(const float4*)&as[k][tx * 4];
      float4 b4 = *(const float4*)&bs[k][ty * 4];
      float av[4] = {a4.x, a4.y, a4.z, a4.w};
      float bv[4] = {b4.x, b4.y, b4.z, b4.w};
#pragma unroll
      for (int i = 0; i < 4; ++i)
#pragma unroll
        for (int j = 0; j < 4; ++j) acc[i][j] += av[i] * bv[j];
    }
  }
#pragma unroll
  for (int i = 0; i < 4; ++i) {
    int m = m0 + tx * 4 + i;
#pragma unroll
    for (int j = 0; j < 4; ++j) {
      int n = n0 + ty * 4 + j;
      float v = (acc[i][j] + bias[BIASM ? m : n]) * alpha;
      size_t idx = (size_t)z * sC + (size_t)m * N + n;
      if (OUT == 0) {
        ((float*)Ch)[idx] = v;
      } else {
        f16 hi = (f16)v;
        ((f16*)Ch)[idx] = hi;
        ((f16*)Cl)[idx] = (f16)((v - (float)hi) * LO_S);
      }
    }
  }
}

// -------- split-fp16 MFMA flash attention (numerically ~fp32) --------
// 512 threads = 8 waves, 128 q-rows/block. Reg-staged K/V prefetch (T14),
// defer-max (T13), setprio on MFMA clusters (T5).
__global__ __launch_bounds__(512, 2) void flashsp(
    const f16* __restrict__ Qh, const f16* __restrict__ Ql,
    const f16* __restrict__ Kh, const f16* __restrict__ Kl,
    const f16* __restrict__ Vh, const f16* __restrict__ Vl,
    float* __restrict__ Ht) {
  int b = blockIdx.y;
  int m0 = blockIdx.x * 128;
  int t = threadIdx.x;
  int lane = t & 63;
  int wv = t >> 6;
  int l15 = lane & 15;
  int koff = (lane >> 4) * 8;
  const f16* Qbh = Qh + (size_t)b * HW_ * C_;
  const f16* Qbl = Ql + (size_t)b * HW_ * C_;
  const f16* Kbh = Kh + (size_t)b * HW_ * C_;
  const f16* Kbl = Kl + (size_t)b * HW_ * C_;
  const f16* Vbh = Vh + (size_t)b * C_ * HW_;
  const f16* Vbl = Vl + (size_t)b * C_ * HW_;

  __shared__ f16 ksh[32][264], ksl[32][264];   // K tile, 528B rows
  __shared__ f16 vsh[256][40], vsl[256][40];   // V^T tile, 80B rows (16B-aligned)
  __shared__ f16 psh[8][16][40], psl[8][16][40];

  int mrow = m0 + wv * 16 + l15;
  half8 qfh[8], qfl[8];
#pragma unroll
  for (int kk = 0; kk < 8; ++kk) {
    qfh[kk] = *(const half8*)(Qbh + (size_t)mrow * C_ + kk * 32 + koff);
    qfl[kk] = *(const half8*)(Qbl + (size_t)mrow * C_ + kk * 32 + koff);
  }

  floatx4 o[16];
#pragma unroll
  for (int i = 0; i < 16; ++i) o[i] = (floatx4){0.f, 0.f, 0.f, 0.f};
  float m_run[4] = {-1e30f, -1e30f, -1e30f, -1e30f};
  float l_run[4] = {0.f, 0.f, 0.f, 0.f};

  // staging assignment: K: 32 rows x 256 f16; each thread 32B of hi + lo
  int krow = t >> 4, kch = (t & 15) * 16;
  // V: 256 rows x 32 f16; each thread 32B of hi + lo
  int vrow = t >> 1, vch = (t & 1) * 16;

  uint4 rkh0, rkh1, rkl0, rkl1, rvh0, rvh1, rvl0, rvl1;

#define LOADT(N0)                                                          \
  {                                                                        \
    const uint4* ph = (const uint4*)(Kbh + (size_t)((N0) + krow) * C_ + kch); \
    const uint4* pl = (const uint4*)(Kbl + (size_t)((N0) + krow) * C_ + kch); \
    rkh0 = ph[0]; rkh1 = ph[1]; rkl0 = pl[0]; rkl1 = pl[1];                \
    const uint4* wh = (const uint4*)(Vbh + (size_t)vrow * HW_ + (N0) + vch);  \
    const uint4* wl = (const uint4*)(Vbl + (size_t)vrow * HW_ + (N0) + vch);  \
    rvh0 = wh[0]; rvh1 = wh[1]; rvl0 = wl[0]; rvl1 = wl[1];                \
  }
#define STORET()                                                           \
  {                                                                        \
    *(uint4*)&ksh[krow][kch] = rkh0; *(uint4*)&ksh[krow][kch + 8] = rkh1;  \
    *(uint4*)&ksl[krow][kch] = rkl0; *(uint4*)&ksl[krow][kch + 8] = rkl1;  \
    *(uint4*)&vsh[vrow][vch] = rvh0; *(uint4*)&vsh[vrow][vch + 8] = rvh1;  \
    *(uint4*)&vsl[vrow][vch] = rvl0; *(uint4*)&vsl[vrow][vch + 8] = rvl1;  \
  }

  LOADT(0);
  STORET();
  __syncthreads();

  for (int n0 = 0; n0 < HW_; n0 += KVB) {
    bool notlast = (n0 + KVB < HW_);
    if (notlast) LOADT(n0 + KVB);        // T14: issue next tile early
    __builtin_amdgcn_sched_barrier(0);   // keep loads above the compute

    floatx4 s0h = {0.f,0.f,0.f,0.f}, s0x = {0.f,0.f,0.f,0.f};
    floatx4 s1h = {0.f,0.f,0.f,0.f}, s1x = {0.f,0.f,0.f,0.f};
    __builtin_amdgcn_s_setprio(1);
#pragma unroll
    for (int kk = 0; kk < 8; ++kk) {
      half8 k0h = *(const half8*)&ksh[l15][kk * 32 + koff];
      half8 k0l = *(const half8*)&ksl[l15][kk * 32 + koff];
      half8 k1h = *(const half8*)&ksh[16 + l15][kk * 32 + koff];
      half8 k1l = *(const half8*)&ksl[16 + l15][kk * 32 + koff];
      s0h = mfma16(qfh[kk], k0h, s0h);
      s0x = mfma16(qfh[kk], k0l, s0x);
      s0x = mfma16(qfl[kk], k0h, s0x);
      s1h = mfma16(qfh[kk], k1h, s1h);
      s1x = mfma16(qfh[kk], k1l, s1x);
      s1x = mfma16(qfl[kk], k1h, s1x);
    }
    __builtin_amdgcn_s_setprio(0);

    float v0a[4], v1a[4], tmax[4];
#pragma unroll
    for (int r = 0; r < 4; ++r) {
      float v0 = s0h[r] + s0x[r] * LO_I;
      float v1 = s1h[r] + s1x[r] * LO_I;
      float tm = fmaxf(v0, v1);
      tm = fmaxf(tm, __shfl_xor(tm, 1));
      tm = fmaxf(tm, __shfl_xor(tm, 2));
      tm = fmaxf(tm, __shfl_xor(tm, 4));
      tm = fmaxf(tm, __shfl_xor(tm, 8));
      v0a[r] = v0; v1a[r] = v1; tmax[r] = tm;
    }
    // T13 defer-max: rescale only when some row's max grew past THR
    int need = (tmax[0] > m_run[0] + DEFER_THR) | (tmax[1] > m_run[1] + DEFER_THR) |
               (tmax[2] > m_run[2] + DEFER_THR) | (tmax[3] > m_run[3] + DEFER_THR);
    if (__any(need)) {
      float sc[4];
#pragma unroll
      for (int r = 0; r < 4; ++r) {
        float mn = fmaxf(m_run[r], tmax[r]);
        sc[r] = __expf(m_run[r] - mn);
        m_run[r] = mn;
        l_run[r] *= sc[r];
      }
#pragma unroll
      for (int i = 0; i < 16; ++i) {
        o[i][0] *= sc[0]; o[i][1] *= sc[1]; o[i][2] *= sc[2]; o[i][3] *= sc[3];
      }
    }
    float p0[4], p1[4];
#pragma unroll
    for (int r = 0; r < 4; ++r) {
      p0[r] = __expf(v0a[r] - m_run[r]);
      p1[r] = __expf(v1a[r] - m_run[r]);
      float su = p0[r] + p1[r];
      su += __shfl_xor(su, 1);
      su += __shfl_xor(su, 2);
      su += __shfl_xor(su, 4);
      su += __shfl_xor(su, 8);
      l_run[r] += su;
    }
#pragma unroll
    for (int r = 0; r < 4; ++r) {
      int mr = (lane >> 4) * 4 + r;
      f16 h0 = (f16)p0[r], h1 = (f16)p1[r];
      psh[wv][mr][l15] = h0;
      psh[wv][mr][16 + l15] = h1;
      psl[wv][mr][l15] = (f16)((p0[r] - (float)h0) * LO_S);
      psl[wv][mr][16 + l15] = (f16)((p1[r] - (float)h1) * LO_S);
    }
    asm volatile("s_waitcnt lgkmcnt(0)" ::: "memory");
    __builtin_amdgcn_sched_barrier(0);
    half8 pfh = *(const half8*)&psh[wv][l15][koff];
    half8 pfl = *(const half8*)&psl[wv][l15][koff];
    __builtin_amdgcn_s_setprio(1);
#pragma unroll
    for (int ct = 0; ct < 16; ++ct) {
      half8 vfh = *(const half8*)&vsh[ct * 16 + l15][koff];
      half8 vfl = *(const half8*)&vsl[ct * 16 + l15][koff];
      floatx4 om = {0.f, 0.f, 0.f, 0.f};
      om = mfma16(pfh, vfl, om);
      om = mfma16(pfl, vfh, om);
      o[ct] = mfma16(pfh, vfh, o[ct]);
      o[ct][0] += om[0] * LO_I; o[ct][1] += om[1] * LO_I;
      o[ct][2] += om[2] * LO_I; o[ct][3] += om[3] * LO_I;
    }
    __builtin_amdgcn_s_setprio(0);

    __syncthreads();            // all waves done reading this tile
    if (notlast) STORET();      // write prefetched tile
    __syncthreads();            // tile ready
  }

  float inv[4];
#pragma unroll
  for (int r = 0; r < 4; ++r) inv[r] = 1.f / l_run[r];
#pragma unroll
  for (int ct = 0; ct < 16; ++ct) {
#pragma unroll
    for (int r = 0; r < 4; ++r) {
      int m = m0 + wv * 16 + (lane >> 4) * 4 + r;
      Ht[((size_t)b * HW_ + m) * C_ + ct * 16 + l15] = o[ct][r] * inv[r];
    }
  }
#undef LOADT
#undef STORET
}

extern "C" void kernel_launch(void* const* d_in, const int* in_sizes, int n_in,
                              void* d_out, int out_size, void* d_ws, size_t ws_size,
                              hipStream_t stream) {
  const float* x   = (const float*)d_in[0];
  const float* tg  = (const float*)d_in[1];
  const float* gsc = (const float*)d_in[2];
  const float* gbi = (const float*)d_in[3];
  const float* Wq  = (const float*)d_in[4];
  const float* bq  = (const float*)d_in[5];
  const float* Wk  = (const float*)d_in[6];
  const float* bk  = (const float*)d_in[7];
  const float* Wv  = (const float*)d_in[8];
  const float* bv  = (const float*)d_in[9];
  const float* Wp  = (const float*)d_in[10];
  const float* bp  = (const float*)d_in[11];

  char* ws = (char*)d_ws;
  size_t off = 0;
  auto alloc = [&](size_t bytes) {
    char* p = ws + off;
    off += (bytes + 255) & ~(size_t)255;
    return p;
  };
  const size_t HSZ = (size_t)B_ * HW_ * C_ * sizeof(f16);   // 16.78 MB
  f16* qh = (f16*)alloc(HSZ);
  f16* ql = (f16*)alloc(HSZ);
  f16* kh = (f16*)alloc(HSZ);
  f16* kl = (f16*)alloc(HSZ);
  f16* vh = (f16*)alloc(HSZ);
  f16* vl = (f16*)alloc(HSZ);
  float* ht = (float*)alloc((size_t)B_ * HW_ * C_ * sizeof(float));  // 33.55 MB
  float* stats = (float*)alloc((size_t)2 * B_ * 32 * 2 * sizeof(float));

  gn_stats<<<dim3(512), dim3(256), 0, stream>>>(x, tg, stats);

  const long sIn = (long)C_ * HW_;
  const long sT  = (long)HW_ * C_;

  // q = (GN(x).Wq^T + bq)*C^-0.5 -> split f16 [B][HW][C]
  gemm32<1, 0, 0, 1><<<dim3(64, 4, 8), dim3(256), 0, stream>>>(
      x, Wq, bq, qh, ql, stats, gsc, gbi, C_, 0.0625f, sIn, 0L, sT);
  // k = GN(tg).Wk^T + bk -> split f16 [B][HW][C]
  gemm32<1, 0, 0, 1><<<dim3(64, 4, 8), dim3(256), 0, stream>>>(
      tg, Wk, bk, kh, kl, stats + 512, gsc, gbi, C_, 1.f, sIn, 0L, sT);
  // vT = Wv.GN(tg)^T + bv -> split f16 [B][C][HW]
  gemm32<0, 1, 1, 1><<<dim3(4, 64, 8), dim3(256), 0, stream>>>(
      Wv, tg, bv, vh, vl, stats + 512, gsc, gbi, HW_, 1.f, 0L, sIn, sT);
  // attention (split-fp16 MFMA, fp32-equivalent)
  flashsp<<<dim3(32, 8), dim3(512), 0, stream>>>(qh, ql, kh, kl, vh, vl, ht);
  // out = Wp.h^T + bp -> [B][C][HW] fp32
  gemm32<0, 0, 1, 0><<<dim3(4, 64, 8), dim3(256), 0, stream>>>(
      Wp, ht, bp, d_out, nullptr, nullptr, nullptr, nullptr,
      HW_, 1.f, 0L, sT, (long)C_ * HW_);
}

// Round 8
// 1056.333 us; speedup vs baseline: 4.4047x; 1.0335x over previous
//
#include <hip/hip_runtime.h>
#include <cstdint>
#include <cstddef>

typedef _Float16 f16;
typedef _Float16 half8 __attribute__((ext_vector_type(8)));
typedef float floatx4 __attribute__((ext_vector_type(4)));

#define B_ 8
#define C_ 256
#define HW_ 4096
#define EPS_ 1e-5f
#define KVB 32
#define DEFER_THR 8.0f        // T13: skip O-rescale while tile max <= m_run + THR

__device__ __forceinline__ floatx4 mfma16(half8 a, half8 b, floatx4 c) {
  return __builtin_amdgcn_mfma_f32_16x16x32_f16(a, b, c, 0, 0, 0);
}

// ---------------- GroupNorm stats: one block per (tensor, b, g) ----------------
__global__ void gn_stats(const float* __restrict__ x, const float* __restrict__ y,
                         float* __restrict__ stats) {
  int bid = blockIdx.x;            // [0, 512)
  int which = bid >> 8;
  int b = (bid >> 5) & 7;
  int g = bid & 31;
  const float* src = which ? y : x;
  const float* base = src + ((size_t)b * C_ + (size_t)g * 8) * HW_;
  float s = 0.f, ss = 0.f;
  const float4* base4 = (const float4*)base;
  for (int i = threadIdx.x; i < 8 * HW_ / 4; i += 256) {
    float4 v = base4[i];
    s += v.x + v.y + v.z + v.w;
    ss += v.x * v.x + v.y * v.y + v.z * v.z + v.w * v.w;
  }
#pragma unroll
  for (int m = 1; m <= 32; m <<= 1) { s += __shfl_xor(s, m); ss += __shfl_xor(ss, m); }
  __shared__ float red[8];
  int wv = threadIdx.x >> 6;
  if ((threadIdx.x & 63) == 0) { red[wv] = s; red[4 + wv] = ss; }
  __syncthreads();
  if (threadIdx.x == 0) {
    float S = red[0] + red[1] + red[2] + red[3];
    float SS = red[4] + red[5] + red[6] + red[7];
    float mean = S / 32768.f;
    float var = SS / 32768.f - mean * mean;
    stats[bid * 2 + 0] = mean;
    stats[bid * 2 + 1] = rsqrtf(var + EPS_);
  }
}

// ---- fp32 GEMM: C[M][N] = (A[M][256] . Bp[N][256]^T + bias) * alpha ----
// AGN/BGN=1: operand from [C][HW] fp32 tensor, transposed + GroupNorm fused.
// OUT=0: fp32 to Ch.  OUT=1: single f16 to Ch.
template<int AGN, int BGN, int BIASM, int OUT>
__global__ __launch_bounds__(256) void gemm32(
    const float* __restrict__ A, const float* __restrict__ Bp,
    const float* __restrict__ bias,
    void* __restrict__ Ch,
    const float* __restrict__ stats, const float* __restrict__ gsc,
    const float* __restrict__ gbi,
    int N, float alpha, long sA, long sB, long sC) {
  __shared__ float as[16][68];   // [k][m]
  __shared__ float bs[16][68];   // [k][n]
  int z = blockIdx.z;
  const float* Ab = A + (size_t)z * sA;
  const float* Bb = Bp + (size_t)z * sB;
  int m0 = blockIdx.x * 64, n0 = blockIdx.y * 64;
  int t = threadIdx.x;
  int tx = t & 15, ty = t >> 4;
  float acc[4][4] = {};
  for (int kk = 0; kk < 256; kk += 16) {
    __syncthreads();
    if (AGN) {
      int kidx = t >> 4, mq = (t & 15) * 4;
      int c = kk + kidx;
      float mu = stats[((size_t)z * 32 + (c >> 3)) * 2 + 0];
      float rs = stats[((size_t)z * 32 + (c >> 3)) * 2 + 1];
      float scl = rs * gsc[c];
      float off = gbi[c] - mu * scl;
      float4 v = *(const float4*)&Ab[(size_t)c * HW_ + m0 + mq];
      float4 o;
      o.x = v.x * scl + off; o.y = v.y * scl + off;
      o.z = v.z * scl + off; o.w = v.w * scl + off;
      *(float4*)&as[kidx][mq] = o;
    } else {
      int m2 = t >> 2, kq = (t & 3) * 4;
      float4 v = *(const float4*)&Ab[(size_t)(m0 + m2) * 256 + kk + kq];
      as[kq + 0][m2] = v.x; as[kq + 1][m2] = v.y;
      as[kq + 2][m2] = v.z; as[kq + 3][m2] = v.w;
    }
    if (BGN) {
      int kidx = t >> 4, nq = (t & 15) * 4;
      int c = kk + kidx;
      float mu = stats[((size_t)z * 32 + (c >> 3)) * 2 + 0];
      float rs = stats[((size_t)z * 32 + (c >> 3)) * 2 + 1];
      float scl = rs * gsc[c];
      float off = gbi[c] - mu * scl;
      float4 v = *(const float4*)&Bb[(size_t)c * HW_ + n0 + nq];
      float4 o;
      o.x = v.x * scl + off; o.y = v.y * scl + off;
      o.z = v.z * scl + off; o.w = v.w * scl + off;
      *(float4*)&bs[kidx][nq] = o;
    } else {
      int n2 = t >> 2, kq = (t & 3) * 4;
      float4 w = *(const float4*)&Bb[(size_t)(n0 + n2) * 256 + kk + kq];
      bs[kq + 0][n2] = w.x; bs[kq + 1][n2] = w.y;
      bs[kq + 2][n2] = w.z; bs[kq + 3][n2] = w.w;
    }
    __syncthreads();
#pragma unroll
    for (int k = 0; k < 16; ++k) {
      float4 a4 = *(const float4*)&as[k][tx * 4];
      float4 b4 = *(const float4*)&bs[k][ty * 4];
      float av[4] = {a4.x, a4.y, a4.z, a4.w};
      float bv[4] = {b4.x, b4.y, b4.z, b4.w};
#pragma unroll
      for (int i = 0; i < 4; ++i)
#pragma unroll
        for (int j = 0; j < 4; ++j) acc[i][j] += av[i] * bv[j];
    }
  }
#pragma unroll
  for (int i = 0; i < 4; ++i) {
    int m = m0 + tx * 4 + i;
#pragma unroll
    for (int j = 0; j < 4; ++j) {
      int n = n0 + ty * 4 + j;
      float v = (acc[i][j] + bias[BIASM ? m : n]) * alpha;
      size_t idx = (size_t)z * sC + (size_t)m * N + n;
      if (OUT == 0) ((float*)Ch)[idx] = v;
      else          ((f16*)Ch)[idx] = (f16)v;
    }
  }
}

// -------- single-fp16 MFMA flash attention, fp32 softmax/accum --------
// Q,K: [B][HW][C] f16; V: [B][C][HW] f16; out Ht: [B][HW][C] fp32.
// 256 thr = 4 waves, 64 q-rows/block. T14 reg prefetch, T13 defer-max,
// T5 setprio, T1 XCD swizzle (batch = flat%8 so each XCD L2 holds one batch).
__global__ __launch_bounds__(256, 2) void flashf(
    const f16* __restrict__ Q, const f16* __restrict__ K,
    const f16* __restrict__ V, float* __restrict__ Ht) {
  int flat = blockIdx.x + blockIdx.y * 64;
  int b = flat & 7;                 // XCD swizzle: consecutive blocks -> distinct batches
  int m0 = (flat >> 3) * 64;
  int t = threadIdx.x;
  int lane = t & 63;
  int wv = t >> 6;
  int l15 = lane & 15;
  int koff = (lane >> 4) * 8;
  const f16* Qb = Q + (size_t)b * HW_ * C_;
  const f16* Kb = K + (size_t)b * HW_ * C_;
  const f16* Vb = V + (size_t)b * C_ * HW_;

  __shared__ f16 ks[32][264];      // K tile 32 x 256 (+8 pad)
  __shared__ f16 vs[256][40];      // V^T tile 256 x 32 (+8 pad)
  __shared__ f16 ps[4][16][40];    // per-wave P tile

  int mrow = m0 + wv * 16 + l15;
  half8 qf[8];
#pragma unroll
  for (int kk = 0; kk < 8; ++kk)
    qf[kk] = *(const half8*)(Qb + (size_t)mrow * C_ + kk * 32 + koff);

  floatx4 o[16];
#pragma unroll
  for (int i = 0; i < 16; ++i) o[i] = (floatx4){0.f, 0.f, 0.f, 0.f};
  float m_run[4] = {-1e30f, -1e30f, -1e30f, -1e30f};
  float l_run[4] = {0.f, 0.f, 0.f, 0.f};

  // staging: K: 32 rows, 8 thr/row x 64B; V: 1 row (32 f16 = 64B) per thread
  int krow = t >> 3, kch = (t & 7) * 32;
  uint4 rk[4], rv[4];

#define LOADT(N0)                                                            \
  {                                                                          \
    const uint4* pk = (const uint4*)(Kb + (size_t)((N0) + krow) * C_ + kch); \
    rk[0] = pk[0]; rk[1] = pk[1]; rk[2] = pk[2]; rk[3] = pk[3];              \
    const uint4* pv = (const uint4*)(Vb + (size_t)t * HW_ + (N0));           \
    rv[0] = pv[0]; rv[1] = pv[1]; rv[2] = pv[2]; rv[3] = pv[3];              \
  }
#define STORET()                                                             \
  {                                                                          \
    uint4* dk = (uint4*)&ks[krow][kch];                                      \
    dk[0] = rk[0]; dk[1] = rk[1]; dk[2] = rk[2]; dk[3] = rk[3];              \
    uint4* dv = (uint4*)&vs[t][0];                                           \
    dv[0] = rv[0]; dv[1] = rv[1]; dv[2] = rv[2]; dv[3] = rv[3];              \
  }

  LOADT(0);
  STORET();
  __syncthreads();

  for (int n0 = 0; n0 < HW_; n0 += KVB) {
    bool notlast = (n0 + KVB < HW_);
    if (notlast) LOADT(n0 + KVB);        // T14: issue next tile's loads early
    __builtin_amdgcn_sched_barrier(0);

    floatx4 s0 = {0.f, 0.f, 0.f, 0.f};
    floatx4 s1 = {0.f, 0.f, 0.f, 0.f};
    __builtin_amdgcn_s_setprio(1);
#pragma unroll
    for (int kk = 0; kk < 8; ++kk) {
      half8 k0 = *(const half8*)&ks[l15][kk * 32 + koff];
      half8 k1 = *(const half8*)&ks[16 + l15][kk * 32 + koff];
      s0 = mfma16(qf[kk], k0, s0);
      s1 = mfma16(qf[kk], k1, s1);
    }
    __builtin_amdgcn_s_setprio(0);

    float v0a[4], v1a[4], tmax[4];
#pragma unroll
    for (int r = 0; r < 4; ++r) {
      float tm = fmaxf(s0[r], s1[r]);
      tm = fmaxf(tm, __shfl_xor(tm, 1));
      tm = fmaxf(tm, __shfl_xor(tm, 2));
      tm = fmaxf(tm, __shfl_xor(tm, 4));
      tm = fmaxf(tm, __shfl_xor(tm, 8));
      v0a[r] = s0[r]; v1a[r] = s1[r]; tmax[r] = tm;
    }
    // T13 defer-max
    int need = (tmax[0] > m_run[0] + DEFER_THR) | (tmax[1] > m_run[1] + DEFER_THR) |
               (tmax[2] > m_run[2] + DEFER_THR) | (tmax[3] > m_run[3] + DEFER_THR);
    if (__any(need)) {
      float sc[4];
#pragma unroll
      for (int r = 0; r < 4; ++r) {
        float mn = fmaxf(m_run[r], tmax[r]);
        sc[r] = __expf(m_run[r] - mn);
        m_run[r] = mn;
        l_run[r] *= sc[r];
      }
#pragma unroll
      for (int i = 0; i < 16; ++i) {
        o[i][0] *= sc[0]; o[i][1] *= sc[1]; o[i][2] *= sc[2]; o[i][3] *= sc[3];
      }
    }
    float p0[4], p1[4];
#pragma unroll
    for (int r = 0; r < 4; ++r) {
      p0[r] = __expf(v0a[r] - m_run[r]);
      p1[r] = __expf(v1a[r] - m_run[r]);
      float su = p0[r] + p1[r];
      su += __shfl_xor(su, 1);
      su += __shfl_xor(su, 2);
      su += __shfl_xor(su, 4);
      su += __shfl_xor(su, 8);
      l_run[r] += su;
    }
#pragma unroll
    for (int r = 0; r < 4; ++r) {
      int mr = (lane >> 4) * 4 + r;
      ps[wv][mr][l15] = (f16)p0[r];
      ps[wv][mr][16 + l15] = (f16)p1[r];
    }
    asm volatile("s_waitcnt lgkmcnt(0)" ::: "memory");
    __builtin_amdgcn_sched_barrier(0);
    half8 pf = *(const half8*)&ps[wv][l15][koff];
    __builtin_amdgcn_s_setprio(1);
#pragma unroll
    for (int ct = 0; ct < 16; ++ct) {
      half8 vf = *(const half8*)&vs[ct * 16 + l15][koff];
      o[ct] = mfma16(pf, vf, o[ct]);
    }
    __builtin_amdgcn_s_setprio(0);

    __syncthreads();            // all waves done reading this tile
    if (notlast) STORET();      // write prefetched tile
    __syncthreads();            // tile ready
  }

  float inv[4];
#pragma unroll
  for (int r = 0; r < 4; ++r) inv[r] = 1.f / l_run[r];
#pragma unroll
  for (int ct = 0; ct < 16; ++ct) {
#pragma unroll
    for (int r = 0; r < 4; ++r) {
      int m = m0 + wv * 16 + (lane >> 4) * 4 + r;
      Ht[((size_t)b * HW_ + m) * C_ + ct * 16 + l15] = o[ct][r] * inv[r];
    }
  }
#undef LOADT
#undef STORET
}

extern "C" void kernel_launch(void* const* d_in, const int* in_sizes, int n_in,
                              void* d_out, int out_size, void* d_ws, size_t ws_size,
                              hipStream_t stream) {
  const float* x   = (const float*)d_in[0];
  const float* tg  = (const float*)d_in[1];
  const float* gsc = (const float*)d_in[2];
  const float* gbi = (const float*)d_in[3];
  const float* Wq  = (const float*)d_in[4];
  const float* bq  = (const float*)d_in[5];
  const float* Wk  = (const float*)d_in[6];
  const float* bk  = (const float*)d_in[7];
  const float* Wv  = (const float*)d_in[8];
  const float* bv  = (const float*)d_in[9];
  const float* Wp  = (const float*)d_in[10];
  const float* bp  = (const float*)d_in[11];

  char* ws = (char*)d_ws;
  size_t off = 0;
  auto alloc = [&](size_t bytes) {
    char* p = ws + off;
    off += (bytes + 255) & ~(size_t)255;
    return p;
  };
  const size_t HSZ = (size_t)B_ * HW_ * C_ * sizeof(f16);   // 16.78 MB
  f16* qh = (f16*)alloc(HSZ);
  f16* kh = (f16*)alloc(HSZ);
  f16* vh = (f16*)alloc(HSZ);
  float* ht = (float*)alloc((size_t)B_ * HW_ * C_ * sizeof(float));  // 33.55 MB
  float* stats = (float*)alloc((size_t)2 * B_ * 32 * 2 * sizeof(float));

  gn_stats<<<dim3(512), dim3(256), 0, stream>>>(x, tg, stats);

  const long sIn = (long)C_ * HW_;
  const long sT  = (long)HW_ * C_;

  // q = (GN(x).Wq^T + bq)*C^-0.5 -> f16 [B][HW][C]
  gemm32<1, 0, 0, 1><<<dim3(64, 4, 8), dim3(256), 0, stream>>>(
      x, Wq, bq, qh, stats, gsc, gbi, C_, 0.0625f, sIn, 0L, sT);
  // k = GN(tg).Wk^T + bk -> f16 [B][HW][C]
  gemm32<1, 0, 0, 1><<<dim3(64, 4, 8), dim3(256), 0, stream>>>(
      tg, Wk, bk, kh, stats + 512, gsc, gbi, C_, 1.f, sIn, 0L, sT);
  // vT = Wv.GN(tg)^T + bv -> f16 [B][C][HW]
  gemm32<0, 1, 1, 1><<<dim3(4, 64, 8), dim3(256), 0, stream>>>(
      Wv, tg, bv, vh, stats + 512, gsc, gbi, HW_, 1.f, 0L, sIn, sT);
  // attention (single-fp16 MFMA, fp32 softmax/accum)
  flashf<<<dim3(64, 8), dim3(256), 0, stream>>>(qh, kh, vh, ht);
  // out = Wp.h^T + bp -> [B][C][HW] fp32
  gemm32<0, 0, 1, 0><<<dim3(4, 64, 8), dim3(256), 0, stream>>>(
      Wp, ht, bp, d_out, nullptr, nullptr, nullptr,
      HW_, 1.f, 0L, sT, (long)C_ * HW_);
}

// Round 9
// 618.073 us; speedup vs baseline: 7.5279x; 1.7091x over previous
//
#include <hip/hip_runtime.h>
#include <cstdint>
#include <cstddef>

typedef _Float16 f16;
typedef _Float16 half8 __attribute__((ext_vector_type(8)));
typedef float floatx4 __attribute__((ext_vector_type(4)));

#define B_ 8
#define C_ 256
#define HW_ 4096
#define EPS_ 1e-5f
#define KVB 32
#define DEFER_THR 8.0f        // T13: skip O-rescale while tile max <= m_run + THR

__device__ __forceinline__ floatx4 mfma16(half8 a, half8 b, floatx4 c) {
  return __builtin_amdgcn_mfma_f32_16x16x32_f16(a, b, c, 0, 0, 0);
}

// ---------------- GroupNorm stats: one block per (tensor, b, g) ----------------
__global__ void gn_stats(const float* __restrict__ x, const float* __restrict__ y,
                         float* __restrict__ stats) {
  int bid = blockIdx.x;            // [0, 512)
  int which = bid >> 8;
  int b = (bid >> 5) & 7;
  int g = bid & 31;
  const float* src = which ? y : x;
  const float* base = src + ((size_t)b * C_ + (size_t)g * 8) * HW_;
  float s = 0.f, ss = 0.f;
  const float4* base4 = (const float4*)base;
  for (int i = threadIdx.x; i < 8 * HW_ / 4; i += 256) {
    float4 v = base4[i];
    s += v.x + v.y + v.z + v.w;
    ss += v.x * v.x + v.y * v.y + v.z * v.z + v.w * v.w;
  }
#pragma unroll
  for (int m = 1; m <= 32; m <<= 1) { s += __shfl_xor(s, m); ss += __shfl_xor(ss, m); }
  __shared__ float red[8];
  int wv = threadIdx.x >> 6;
  if ((threadIdx.x & 63) == 0) { red[wv] = s; red[4 + wv] = ss; }
  __syncthreads();
  if (threadIdx.x == 0) {
    float S = red[0] + red[1] + red[2] + red[3];
    float SS = red[4] + red[5] + red[6] + red[7];
    float mean = S / 32768.f;
    float var = SS / 32768.f - mean * mean;
    stats[bid * 2 + 0] = mean;
    stats[bid * 2 + 1] = rsqrtf(var + EPS_);
  }
}

// ---- fp32 GEMM: C[M][N] = (A[M][256] . Bp[N][256]^T + bias) * alpha ----
// AGN/BGN=1: operand from [C][HW] fp32 tensor, transposed + GroupNorm fused.
// OUT=0: fp32 to Ch.  OUT=1: single f16 to Ch.
template<int AGN, int BGN, int BIASM, int OUT>
__global__ __launch_bounds__(256) void gemm32(
    const float* __restrict__ A, const float* __restrict__ Bp,
    const float* __restrict__ bias,
    void* __restrict__ Ch,
    const float* __restrict__ stats, const float* __restrict__ gsc,
    const float* __restrict__ gbi,
    int N, float alpha, long sA, long sB, long sC) {
  __shared__ float as[16][68];   // [k][m]
  __shared__ float bs[16][68];   // [k][n]
  int z = blockIdx.z;
  const float* Ab = A + (size_t)z * sA;
  const float* Bb = Bp + (size_t)z * sB;
  int m0 = blockIdx.x * 64, n0 = blockIdx.y * 64;
  int t = threadIdx.x;
  int tx = t & 15, ty = t >> 4;
  float acc[4][4] = {};
  for (int kk = 0; kk < 256; kk += 16) {
    __syncthreads();
    if (AGN) {
      int kidx = t >> 4, mq = (t & 15) * 4;
      int c = kk + kidx;
      float mu = stats[((size_t)z * 32 + (c >> 3)) * 2 + 0];
      float rs = stats[((size_t)z * 32 + (c >> 3)) * 2 + 1];
      float scl = rs * gsc[c];
      float off = gbi[c] - mu * scl;
      float4 v = *(const float4*)&Ab[(size_t)c * HW_ + m0 + mq];
      float4 o;
      o.x = v.x * scl + off; o.y = v.y * scl + off;
      o.z = v.z * scl + off; o.w = v.w * scl + off;
      *(float4*)&as[kidx][mq] = o;
    } else {
      int m2 = t >> 2, kq = (t & 3) * 4;
      float4 v = *(const float4*)&Ab[(size_t)(m0 + m2) * 256 + kk + kq];
      as[kq + 0][m2] = v.x; as[kq + 1][m2] = v.y;
      as[kq + 2][m2] = v.z; as[kq + 3][m2] = v.w;
    }
    if (BGN) {
      int kidx = t >> 4, nq = (t & 15) * 4;
      int c = kk + kidx;
      float mu = stats[((size_t)z * 32 + (c >> 3)) * 2 + 0];
      float rs = stats[((size_t)z * 32 + (c >> 3)) * 2 + 1];
      float scl = rs * gsc[c];
      float off = gbi[c] - mu * scl;
      float4 v = *(const float4*)&Bb[(size_t)c * HW_ + n0 + nq];
      float4 o;
      o.x = v.x * scl + off; o.y = v.y * scl + off;
      o.z = v.z * scl + off; o.w = v.w * scl + off;
      *(float4*)&bs[kidx][nq] = o;
    } else {
      int n2 = t >> 2, kq = (t & 3) * 4;
      float4 w = *(const float4*)&Bb[(size_t)(n0 + n2) * 256 + kk + kq];
      bs[kq + 0][n2] = w.x; bs[kq + 1][n2] = w.y;
      bs[kq + 2][n2] = w.z; bs[kq + 3][n2] = w.w;
    }
    __syncthreads();
#pragma unroll
    for (int k = 0; k < 16; ++k) {
      float4 a4 = *(const float4*)&as[k][tx * 4];
      float4 b4 = *(const float4*)&bs[k][ty * 4];
      float av[4] = {a4.x, a4.y, a4.z, a4.w};
      float bv[4] = {b4.x, b4.y, b4.z, b4.w};
#pragma unroll
      for (int i = 0; i < 4; ++i)
#pragma unroll
        for (int j = 0; j < 4; ++j) acc[i][j] += av[i] * bv[j];
    }
  }
#pragma unroll
  for (int i = 0; i < 4; ++i) {
    int m = m0 + tx * 4 + i;
#pragma unroll
    for (int j = 0; j < 4; ++j) {
      int n = n0 + ty * 4 + j;
      float v = (acc[i][j] + bias[BIASM ? m : n]) * alpha;
      size_t idx = (size_t)z * sC + (size_t)m * N + n;
      if (OUT == 0) ((float*)Ch)[idx] = v;
      else          ((f16*)Ch)[idx] = (f16)v;
    }
  }
}

// -------- single-fp16 MFMA flash attention, fp32 softmax/accum --------
// Q,K: [B][HW][C] f16; V: [B][C][HW] f16; out Ht: [B][HW][C] fp32.
// 512 thr = 8 waves, 128 q-rows/block. Direct LDS staging (low-divergence
// V assignment: 2 thr/row -> 32 lines/inst), T13 defer-max, T5 setprio,
// T1 XCD swizzle (b = blk&7: each XCD's L2 caches exactly one batch's K+V).
__global__ __launch_bounds__(512, 1) void flashf(
    const f16* __restrict__ Q, const f16* __restrict__ K,
    const f16* __restrict__ V, float* __restrict__ Ht) {
  int flat = blockIdx.x;            // [0, 256)
  int b = flat & 7;
  int m0 = (flat >> 3) * 128;
  int t = threadIdx.x;
  int lane = t & 63;
  int wv = t >> 6;
  int l15 = lane & 15;
  int koff = (lane >> 4) * 8;
  const f16* Qb = Q + (size_t)b * HW_ * C_;
  const f16* Kb = K + (size_t)b * HW_ * C_;
  const f16* Vb = V + (size_t)b * C_ * HW_;

  __shared__ f16 ks[32][264];      // K tile 32 x 256 (+8 pad)
  __shared__ f16 vs[256][40];      // V^T tile 256 x 32 (+8 pad)
  __shared__ f16 ps[8][16][40];    // per-wave P tile

  int mrow = m0 + wv * 16 + l15;
  half8 qf[8];
#pragma unroll
  for (int kk = 0; kk < 8; ++kk)
    qf[kk] = *(const half8*)(Qb + (size_t)mrow * C_ + kk * 32 + koff);

  floatx4 o[16];
#pragma unroll
  for (int i = 0; i < 16; ++i) o[i] = (floatx4){0.f, 0.f, 0.f, 0.f};
  float m_run[4] = {-1e30f, -1e30f, -1e30f, -1e30f};
  float l_run[4] = {0.f, 0.f, 0.f, 0.f};

  // staging: K: 16 thr/row x 32B (coalesced); V: 2 thr/row x 32B (32 lines/inst)
  int krow = t >> 4, kch = (t & 15) * 16;
  int vrow = t >> 1, vch = (t & 1) * 16;

  for (int n0 = 0; n0 < HW_; n0 += KVB) {
    __syncthreads();
    {
      const uint4* pk = (const uint4*)(Kb + (size_t)(n0 + krow) * C_ + kch);
      uint4 a0 = pk[0], a1 = pk[1];
      const uint4* pv = (const uint4*)(Vb + (size_t)vrow * HW_ + n0 + vch);
      uint4 b0 = pv[0], b1 = pv[1];
      uint4* dk = (uint4*)&ks[krow][kch];
      dk[0] = a0; dk[1] = a1;
      uint4* dv = (uint4*)&vs[vrow][vch];
      dv[0] = b0; dv[1] = b1;
    }
    __syncthreads();

    floatx4 s0 = {0.f, 0.f, 0.f, 0.f};
    floatx4 s1 = {0.f, 0.f, 0.f, 0.f};
    __builtin_amdgcn_s_setprio(1);
#pragma unroll
    for (int kk = 0; kk < 8; ++kk) {
      half8 k0 = *(const half8*)&ks[l15][kk * 32 + koff];
      half8 k1 = *(const half8*)&ks[16 + l15][kk * 32 + koff];
      s0 = mfma16(qf[kk], k0, s0);
      s1 = mfma16(qf[kk], k1, s1);
    }
    __builtin_amdgcn_s_setprio(0);

    float tmax[4];
#pragma unroll
    for (int r = 0; r < 4; ++r) {
      float tm = fmaxf(s0[r], s1[r]);
      tm = fmaxf(tm, __shfl_xor(tm, 1));
      tm = fmaxf(tm, __shfl_xor(tm, 2));
      tm = fmaxf(tm, __shfl_xor(tm, 4));
      tm = fmaxf(tm, __shfl_xor(tm, 8));
      tmax[r] = tm;
    }
    // T13 defer-max
    int need = (tmax[0] > m_run[0] + DEFER_THR) | (tmax[1] > m_run[1] + DEFER_THR) |
               (tmax[2] > m_run[2] + DEFER_THR) | (tmax[3] > m_run[3] + DEFER_THR);
    if (__any(need)) {
      float sc[4];
#pragma unroll
      for (int r = 0; r < 4; ++r) {
        float mn = fmaxf(m_run[r], tmax[r]);
        sc[r] = __expf(m_run[r] - mn);
        m_run[r] = mn;
        l_run[r] *= sc[r];
      }
#pragma unroll
      for (int i = 0; i < 16; ++i) {
        o[i][0] *= sc[0]; o[i][1] *= sc[1]; o[i][2] *= sc[2]; o[i][3] *= sc[3];
      }
    }
    float p0[4], p1[4];
#pragma unroll
    for (int r = 0; r < 4; ++r) {
      p0[r] = __expf(s0[r] - m_run[r]);
      p1[r] = __expf(s1[r] - m_run[r]);
      float su = p0[r] + p1[r];
      su += __shfl_xor(su, 1);
      su += __shfl_xor(su, 2);
      su += __shfl_xor(su, 4);
      su += __shfl_xor(su, 8);
      l_run[r] += su;
    }
#pragma unroll
    for (int r = 0; r < 4; ++r) {
      int mr = (lane >> 4) * 4 + r;
      ps[wv][mr][l15] = (f16)p0[r];
      ps[wv][mr][16 + l15] = (f16)p1[r];
    }
    asm volatile("s_waitcnt lgkmcnt(0)" ::: "memory");
    __builtin_amdgcn_sched_barrier(0);
    half8 pf = *(const half8*)&ps[wv][l15][koff];
    __builtin_amdgcn_s_setprio(1);
#pragma unroll
    for (int ct = 0; ct < 16; ++ct) {
      half8 vf = *(const half8*)&vs[ct * 16 + l15][koff];
      o[ct] = mfma16(pf, vf, o[ct]);
    }
    __builtin_amdgcn_s_setprio(0);
  }

  float inv[4];
#pragma unroll
  for (int r = 0; r < 4; ++r) inv[r] = 1.f / l_run[r];
#pragma unroll
  for (int ct = 0; ct < 16; ++ct) {
#pragma unroll
    for (int r = 0; r < 4; ++r) {
      int m = m0 + wv * 16 + (lane >> 4) * 4 + r;
      Ht[((size_t)b * HW_ + m) * C_ + ct * 16 + l15] = o[ct][r] * inv[r];
    }
  }
}

extern "C" void kernel_launch(void* const* d_in, const int* in_sizes, int n_in,
                              void* d_out, int out_size, void* d_ws, size_t ws_size,
                              hipStream_t stream) {
  const float* x   = (const float*)d_in[0];
  const float* tg  = (const float*)d_in[1];
  const float* gsc = (const float*)d_in[2];
  const float* gbi = (const float*)d_in[3];
  const float* Wq  = (const float*)d_in[4];
  const float* bq  = (const float*)d_in[5];
  const float* Wk  = (const float*)d_in[6];
  const float* bk  = (const float*)d_in[7];
  const float* Wv  = (const float*)d_in[8];
  const float* bv  = (const float*)d_in[9];
  const float* Wp  = (const float*)d_in[10];
  const float* bp  = (const float*)d_in[11];

  char* ws = (char*)d_ws;
  size_t off = 0;
  auto alloc = [&](size_t bytes) {
    char* p = ws + off;
    off += (bytes + 255) & ~(size_t)255;
    return p;
  };
  const size_t HSZ = (size_t)B_ * HW_ * C_ * sizeof(f16);   // 16.78 MB
  f16* qh = (f16*)alloc(HSZ);
  f16* kh = (f16*)alloc(HSZ);
  f16* vh = (f16*)alloc(HSZ);
  float* ht = (float*)alloc((size_t)B_ * HW_ * C_ * sizeof(float));  // 33.55 MB
  float* stats = (float*)alloc((size_t)2 * B_ * 32 * 2 * sizeof(float));

  gn_stats<<<dim3(512), dim3(256), 0, stream>>>(x, tg, stats);

  const long sIn = (long)C_ * HW_;
  const long sT  = (long)HW_ * C_;

  // q = (GN(x).Wq^T + bq)*C^-0.5 -> f16 [B][HW][C]
  gemm32<1, 0, 0, 1><<<dim3(64, 4, 8), dim3(256), 0, stream>>>(
      x, Wq, bq, qh, stats, gsc, gbi, C_, 0.0625f, sIn, 0L, sT);
  // k = GN(tg).Wk^T + bk -> f16 [B][HW][C]
  gemm32<1, 0, 0, 1><<<dim3(64, 4, 8), dim3(256), 0, stream>>>(
      tg, Wk, bk, kh, stats + 512, gsc, gbi, C_, 1.f, sIn, 0L, sT);
  // vT = Wv.GN(tg)^T + bv -> f16 [B][C][HW]
  gemm32<0, 1, 1, 1><<<dim3(4, 64, 8), dim3(256), 0, stream>>>(
      Wv, tg, bv, vh, stats + 512, gsc, gbi, HW_, 1.f, 0L, sIn, sT);
  // attention (single-fp16 MFMA, fp32 softmax/accum)
  flashf<<<dim3(256), dim3(512), 0, stream>>>(qh, kh, vh, ht);
  // out = Wp.h^T + bp -> [B][C][HW] fp32
  gemm32<0, 0, 1, 0><<<dim3(4, 64, 8), dim3(256), 0, stream>>>(
      Wp, ht, bp, d_out, nullptr, nullptr, nullptr,
      HW_, 1.f, 0L, sT, (long)C_ * HW_);
}

// Round 10
// 487.467 us; speedup vs baseline: 9.5448x; 1.2679x over previous
//
#include <hip/hip_runtime.h>
#include <cstdint>
#include <cstddef>

typedef _Float16 f16;
typedef _Float16 half8 __attribute__((ext_vector_type(8)));
typedef float floatx4 __attribute__((ext_vector_type(4)));

#define B_ 8
#define C_ 256
#define HW_ 4096
#define EPS_ 1e-5f
#define KVB 32
#define DEFER_THR 8.0f        // T13: rescale only when tile max > m_run + THR

__device__ __forceinline__ floatx4 mfma16(half8 a, half8 b, floatx4 c) {
  return __builtin_amdgcn_mfma_f32_16x16x32_f16(a, b, c, 0, 0, 0);
}

// ---------------- GroupNorm stats: one block per (tensor, b, g) ----------------
__global__ void gn_stats(const float* __restrict__ x, const float* __restrict__ y,
                         float* __restrict__ stats) {
  int bid = blockIdx.x;            // [0, 512)
  int which = bid >> 8;
  int b = (bid >> 5) & 7;
  int g = bid & 31;
  const float* src = which ? y : x;
  const float* base = src + ((size_t)b * C_ + (size_t)g * 8) * HW_;
  float s = 0.f, ss = 0.f;
  const float4* base4 = (const float4*)base;
  for (int i = threadIdx.x; i < 8 * HW_ / 4; i += 256) {
    float4 v = base4[i];
    s += v.x + v.y + v.z + v.w;
    ss += v.x * v.x + v.y * v.y + v.z * v.z + v.w * v.w;
  }
#pragma unroll
  for (int m = 1; m <= 32; m <<= 1) { s += __shfl_xor(s, m); ss += __shfl_xor(ss, m); }
  __shared__ float red[8];
  int wv = threadIdx.x >> 6;
  if ((threadIdx.x & 63) == 0) { red[wv] = s; red[4 + wv] = ss; }
  __syncthreads();
  if (threadIdx.x == 0) {
    float S = red[0] + red[1] + red[2] + red[3];
    float SS = red[4] + red[5] + red[6] + red[7];
    float mean = S / 32768.f;
    float var = SS / 32768.f - mean * mean;
    stats[bid * 2 + 0] = mean;
    stats[bid * 2 + 1] = rsqrtf(var + EPS_);
  }
}

// ---- fp32 GEMM: C[M][N] = (A[M][256] . Bp[N][256]^T + bias) * alpha ----
// AGN/BGN=1: operand from [C][HW] fp32 tensor, transposed + GroupNorm fused.
// OUT=0: fp32 to Ch.  OUT=1: single f16 to Ch.
template<int AGN, int BGN, int BIASM, int OUT>
__global__ __launch_bounds__(256) void gemm32(
    const float* __restrict__ A, const float* __restrict__ Bp,
    const float* __restrict__ bias,
    void* __restrict__ Ch,
    const float* __restrict__ stats, const float* __restrict__ gsc,
    const float* __restrict__ gbi,
    int N, float alpha, long sA, long sB, long sC) {
  __shared__ float as[16][68];   // [k][m]
  __shared__ float bs[16][68];   // [k][n]
  int z = blockIdx.z;
  const float* Ab = A + (size_t)z * sA;
  const float* Bb = Bp + (size_t)z * sB;
  int m0 = blockIdx.x * 64, n0 = blockIdx.y * 64;
  int t = threadIdx.x;
  int tx = t & 15, ty = t >> 4;
  float acc[4][4] = {};
  for (int kk = 0; kk < 256; kk += 16) {
    __syncthreads();
    if (AGN) {
      int kidx = t >> 4, mq = (t & 15) * 4;
      int c = kk + kidx;
      float mu = stats[((size_t)z * 32 + (c >> 3)) * 2 + 0];
      float rs = stats[((size_t)z * 32 + (c >> 3)) * 2 + 1];
      float scl = rs * gsc[c];
      float off = gbi[c] - mu * scl;
      float4 v = *(const float4*)&Ab[(size_t)c * HW_ + m0 + mq];
      float4 o;
      o.x = v.x * scl + off; o.y = v.y * scl + off;
      o.z = v.z * scl + off; o.w = v.w * scl + off;
      *(float4*)&as[kidx][mq] = o;
    } else {
      int m2 = t >> 2, kq = (t & 3) * 4;
      float4 v = *(const float4*)&Ab[(size_t)(m0 + m2) * 256 + kk + kq];
      as[kq + 0][m2] = v.x; as[kq + 1][m2] = v.y;
      as[kq + 2][m2] = v.z; as[kq + 3][m2] = v.w;
    }
    if (BGN) {
      int kidx = t >> 4, nq = (t & 15) * 4;
      int c = kk + kidx;
      float mu = stats[((size_t)z * 32 + (c >> 3)) * 2 + 0];
      float rs = stats[((size_t)z * 32 + (c >> 3)) * 2 + 1];
      float scl = rs * gsc[c];
      float off = gbi[c] - mu * scl;
      float4 v = *(const float4*)&Bb[(size_t)c * HW_ + n0 + nq];
      float4 o;
      o.x = v.x * scl + off; o.y = v.y * scl + off;
      o.z = v.z * scl + off; o.w = v.w * scl + off;
      *(float4*)&bs[kidx][nq] = o;
    } else {
      int n2 = t >> 2, kq = (t & 3) * 4;
      float4 w = *(const float4*)&Bb[(size_t)(n0 + n2) * 256 + kk + kq];
      bs[kq + 0][n2] = w.x; bs[kq + 1][n2] = w.y;
      bs[kq + 2][n2] = w.z; bs[kq + 3][n2] = w.w;
    }
    __syncthreads();
#pragma unroll
    for (int k = 0; k < 16; ++k) {
      float4 a4 = *(const float4*)&as[k][tx * 4];
      float4 b4 = *(const float4*)&bs[k][ty * 4];
      float av[4] = {a4.x, a4.y, a4.z, a4.w};
      float bv[4] = {b4.x, b4.y, b4.z, b4.w};
#pragma unroll
      for (int i = 0; i < 4; ++i)
#pragma unroll
        for (int j = 0; j < 4; ++j) acc[i][j] += av[i] * bv[j];
    }
  }
#pragma unroll
  for (int i = 0; i < 4; ++i) {
    int m = m0 + tx * 4 + i;
#pragma unroll
    for (int j = 0; j < 4; ++j) {
      int n = n0 + ty * 4 + j;
      float v = (acc[i][j] + bias[BIASM ? m : n]) * alpha;
      size_t idx = (size_t)z * sC + (size_t)m * N + n;
      if (OUT == 0) ((float*)Ch)[idx] = v;
      else          ((f16*)Ch)[idx] = (f16)v;
    }
  }
}

// -------- single-fp16 MFMA flash attention, fp32 softmax/accum --------
// Q,K: [B][HW][C] f16; V: [B][C][HW] f16; out Ht: [B][HW][C] fp32.
// 512 thr = 8 waves, 128 q-rows/block. Double-buffered LDS + reg prefetch
// (1 barrier/iter), lazy defer-max (no shuffles common path), ones-MFMA
// softmax denominator, T5 setprio, T1 XCD swizzle.
__global__ __launch_bounds__(512, 1) void flashf(
    const f16* __restrict__ Q, const f16* __restrict__ K,
    const f16* __restrict__ V, float* __restrict__ Ht) {
  int flat = blockIdx.x;            // [0, 256)
  int b = flat & 7;
  int m0 = (flat >> 3) * 128;
  int t = threadIdx.x;
  int lane = t & 63;
  int wv = t >> 6;
  int l15 = lane & 15;
  int koff = (lane >> 4) * 8;
  const f16* Qb = Q + (size_t)b * HW_ * C_;
  const f16* Kb = K + (size_t)b * HW_ * C_;
  const f16* Vb = V + (size_t)b * C_ * HW_;

  __shared__ f16 ks[2][32][264];   // K tile dbuf (33 KB)
  __shared__ f16 vs[2][256][40];   // V^T tile dbuf (40 KB)
  __shared__ f16 ps[8][16][40];    // per-wave P tile (10 KB)

  int mrow = m0 + wv * 16 + l15;
  half8 qf[8];
#pragma unroll
  for (int kk = 0; kk < 8; ++kk)
    qf[kk] = *(const half8*)(Qb + (size_t)mrow * C_ + kk * 32 + koff);

  floatx4 o[16];
#pragma unroll
  for (int i = 0; i < 16; ++i) o[i] = (floatx4){0.f, 0.f, 0.f, 0.f};
  floatx4 osum = (floatx4){0.f, 0.f, 0.f, 0.f};   // softmax denominator via ones-MFMA
  float m_run[4] = {-1e30f, -1e30f, -1e30f, -1e30f};

  // staging: K: 16 thr/row x 32B (coalesced); V: 2 thr/row x 32B
  int krow = t >> 4, kch = (t & 15) * 16;
  int vrow = t >> 1, vch = (t & 1) * 16;
  uint4 rk0, rk1, rv0, rv1;

#define LOADT(N0)                                                            \
  {                                                                          \
    const uint4* pk = (const uint4*)(Kb + (size_t)((N0) + krow) * C_ + kch); \
    rk0 = pk[0]; rk1 = pk[1];                                                \
    const uint4* pv = (const uint4*)(Vb + (size_t)vrow * HW_ + (N0) + vch);  \
    rv0 = pv[0]; rv1 = pv[1];                                                \
  }
#define STORET(BUF)                                                          \
  {                                                                          \
    uint4* dk = (uint4*)&ks[BUF][krow][kch];                                 \
    dk[0] = rk0; dk[1] = rk1;                                                \
    uint4* dv = (uint4*)&vs[BUF][vrow][vch];                                 \
    dv[0] = rv0; dv[1] = rv1;                                                \
  }

  LOADT(0);
  STORET(0);
  LOADT(KVB);                      // prefetch tile 1 into registers
  __syncthreads();

  const half8 ones = {(f16)1, (f16)1, (f16)1, (f16)1,
                      (f16)1, (f16)1, (f16)1, (f16)1};

  int cur = 0;
  for (int n0 = 0; n0 < HW_; n0 += KVB) {
    floatx4 s0 = {0.f, 0.f, 0.f, 0.f};
    floatx4 s1 = {0.f, 0.f, 0.f, 0.f};
    __builtin_amdgcn_s_setprio(1);
#pragma unroll
    for (int kk = 0; kk < 8; ++kk) {
      half8 k0 = *(const half8*)&ks[cur][l15][kk * 32 + koff];
      half8 k1 = *(const half8*)&ks[cur][16 + l15][kk * 32 + koff];
      s0 = mfma16(qf[kk], k0, s0);
      s1 = mfma16(qf[kk], k1, s1);
    }
    __builtin_amdgcn_s_setprio(0);

    // lazy defer-max: VALU compares only; shuffle-reduce only on trigger
    int trig = 0;
#pragma unroll
    for (int r = 0; r < 4; ++r) {
      float thr = m_run[r] + DEFER_THR;
      trig |= (s0[r] > thr) | (s1[r] > thr);
    }
    if (__any(trig)) {
      float sc[4];
#pragma unroll
      for (int r = 0; r < 4; ++r) {
        float tm = fmaxf(s0[r], s1[r]);
        tm = fmaxf(tm, __shfl_xor(tm, 1));
        tm = fmaxf(tm, __shfl_xor(tm, 2));
        tm = fmaxf(tm, __shfl_xor(tm, 4));
        tm = fmaxf(tm, __shfl_xor(tm, 8));
        float mn = fmaxf(m_run[r], tm);
        sc[r] = __expf(m_run[r] - mn);
        m_run[r] = mn;
      }
      osum[0] *= sc[0]; osum[1] *= sc[1]; osum[2] *= sc[2]; osum[3] *= sc[3];
#pragma unroll
      for (int i = 0; i < 16; ++i) {
        o[i][0] *= sc[0]; o[i][1] *= sc[1]; o[i][2] *= sc[2]; o[i][3] *= sc[3];
      }
    }
#pragma unroll
    for (int r = 0; r < 4; ++r) {
      float p0 = __expf(s0[r] - m_run[r]);
      float p1 = __expf(s1[r] - m_run[r]);
      int mr = (lane >> 4) * 4 + r;
      ps[wv][mr][l15] = (f16)p0;
      ps[wv][mr][16 + l15] = (f16)p1;
    }
    asm volatile("s_waitcnt lgkmcnt(0)" ::: "memory");
    __builtin_amdgcn_sched_barrier(0);
    half8 pf = *(const half8*)&ps[wv][l15][koff];
    __builtin_amdgcn_s_setprio(1);
#pragma unroll
    for (int ct = 0; ct < 16; ++ct) {
      half8 vf = *(const half8*)&vs[cur][ct * 16 + l15][koff];
      o[ct] = mfma16(pf, vf, o[ct]);
    }
    osum = mfma16(pf, ones, osum);   // denominator: row-sum of the same fp16 P
    __builtin_amdgcn_s_setprio(0);

    bool h1 = n0 + KVB < HW_;
    bool h2 = n0 + 2 * KVB < HW_;
    if (h1) STORET(cur ^ 1);         // vmcnt-waits on loads issued one iter ago
    if (h2) LOADT(n0 + 2 * KVB);     // issue next-next tile (hidden under next compute)
    __syncthreads();
    cur ^= 1;
  }

  float inv[4];
#pragma unroll
  for (int r = 0; r < 4; ++r) inv[r] = 1.f / osum[r];
#pragma unroll
  for (int ct = 0; ct < 16; ++ct) {
#pragma unroll
    for (int r = 0; r < 4; ++r) {
      int m = m0 + wv * 16 + (lane >> 4) * 4 + r;
      Ht[((size_t)b * HW_ + m) * C_ + ct * 16 + l15] = o[ct][r] * inv[r];
    }
  }
#undef LOADT
#undef STORET
}

extern "C" void kernel_launch(void* const* d_in, const int* in_sizes, int n_in,
                              void* d_out, int out_size, void* d_ws, size_t ws_size,
                              hipStream_t stream) {
  const float* x   = (const float*)d_in[0];
  const float* tg  = (const float*)d_in[1];
  const float* gsc = (const float*)d_in[2];
  const float* gbi = (const float*)d_in[3];
  const float* Wq  = (const float*)d_in[4];
  const float* bq  = (const float*)d_in[5];
  const float* Wk  = (const float*)d_in[6];
  const float* bk  = (const float*)d_in[7];
  const float* Wv  = (const float*)d_in[8];
  const float* bv  = (const float*)d_in[9];
  const float* Wp  = (const float*)d_in[10];
  const float* bp  = (const float*)d_in[11];

  char* ws = (char*)d_ws;
  size_t off = 0;
  auto alloc = [&](size_t bytes) {
    char* p = ws + off;
    off += (bytes + 255) & ~(size_t)255;
    return p;
  };
  const size_t HSZ = (size_t)B_ * HW_ * C_ * sizeof(f16);   // 16.78 MB
  f16* qh = (f16*)alloc(HSZ);
  f16* kh = (f16*)alloc(HSZ);
  f16* vh = (f16*)alloc(HSZ);
  float* ht = (float*)alloc((size_t)B_ * HW_ * C_ * sizeof(float));  // 33.55 MB
  float* stats = (float*)alloc((size_t)2 * B_ * 32 * 2 * sizeof(float));

  gn_stats<<<dim3(512), dim3(256), 0, stream>>>(x, tg, stats);

  const long sIn = (long)C_ * HW_;
  const long sT  = (long)HW_ * C_;

  // q = (GN(x).Wq^T + bq)*C^-0.5 -> f16 [B][HW][C]
  gemm32<1, 0, 0, 1><<<dim3(64, 4, 8), dim3(256), 0, stream>>>(
      x, Wq, bq, qh, stats, gsc, gbi, C_, 0.0625f, sIn, 0L, sT);
  // k = GN(tg).Wk^T + bk -> f16 [B][HW][C]
  gemm32<1, 0, 0, 1><<<dim3(64, 4, 8), dim3(256), 0, stream>>>(
      tg, Wk, bk, kh, stats + 512, gsc, gbi, C_, 1.f, sIn, 0L, sT);
  // vT = Wv.GN(tg)^T + bv -> f16 [B][C][HW]
  gemm32<0, 1, 1, 1><<<dim3(4, 64, 8), dim3(256), 0, stream>>>(
      Wv, tg, bv, vh, stats + 512, gsc, gbi, HW_, 1.f, 0L, sIn, sT);
  // attention (single-fp16 MFMA, fp32 softmax/accum)
  flashf<<<dim3(256), dim3(512), 0, stream>>>(qh, kh, vh, ht);
  // out = Wp.h^T + bp -> [B][C][HW] fp32
  gemm32<0, 0, 1, 0><<<dim3(4, 64, 8), dim3(256), 0, stream>>>(
      Wp, ht, bp, d_out, nullptr, nullptr, nullptr,
      HW_, 1.f, 0L, sT, (long)C_ * HW_);
}

// Round 11
// 322.760 us; speedup vs baseline: 14.4156x; 1.5103x over previous
//
#include <hip/hip_runtime.h>
#include <cstdint>
#include <cstddef>

typedef _Float16 f16;
typedef _Float16 half8 __attribute__((ext_vector_type(8)));
typedef float floatx4 __attribute__((ext_vector_type(4)));

#define B_ 8
#define C_ 256
#define HW_ 4096
#define EPS_ 1e-5f
#define KVB 32
#define DEFER_THR 8.0f        // rescale only when tile max > m_run + THR
#define WP_S 65536.0f         // Wp pre-scale (raw Wp ~1e-6 is fp16-subnormal)
#define WP_I (1.0f / 65536.0f)

__device__ __forceinline__ floatx4 mfma16(half8 a, half8 b, floatx4 c) {
  return __builtin_amdgcn_mfma_f32_16x16x32_f16(a, b, c, 0, 0, 0);
}

// ---------------- GroupNorm stats: one block per (tensor, b, g) ----------------
__global__ void gn_stats(const float* __restrict__ x, const float* __restrict__ y,
                         float* __restrict__ stats) {
  int bid = blockIdx.x;            // [0, 512)
  int which = bid >> 8;
  int b = (bid >> 5) & 7;
  int g = bid & 31;
  const float* src = which ? y : x;
  const float* base = src + ((size_t)b * C_ + (size_t)g * 8) * HW_;
  float s = 0.f, ss = 0.f;
  const float4* base4 = (const float4*)base;
  for (int i = threadIdx.x; i < 8 * HW_ / 4; i += 256) {
    float4 v = base4[i];
    s += v.x + v.y + v.z + v.w;
    ss += v.x * v.x + v.y * v.y + v.z * v.z + v.w * v.w;
  }
#pragma unroll
  for (int m = 1; m <= 32; m <<= 1) { s += __shfl_xor(s, m); ss += __shfl_xor(ss, m); }
  __shared__ float red[8];
  int wv = threadIdx.x >> 6;
  if ((threadIdx.x & 63) == 0) { red[wv] = s; red[4 + wv] = ss; }
  __syncthreads();
  if (threadIdx.x == 0) {
    float S = red[0] + red[1] + red[2] + red[3];
    float SS = red[4] + red[5] + red[6] + red[7];
    float mean = S / 32768.f;
    float var = SS / 32768.f - mean * mean;
    stats[bid * 2 + 0] = mean;
    stats[bid * 2 + 1] = rsqrtf(var + EPS_);
  }
}

// ------- GroupNorm apply + transpose: [B][C][HW] fp32 -> [B][HW][C] f16 -------
__global__ void gn_apply(const float* __restrict__ x, const float* __restrict__ y,
                         const float* __restrict__ stats,
                         const float* __restrict__ gsc, const float* __restrict__ gbi,
                         f16* __restrict__ hx, f16* __restrict__ hy) {
  int bid = blockIdx.x;            // [0, 2048)
  int which = bid >> 10;
  int b = (bid >> 7) & 7;
  int hw0 = (bid & 127) * 32;
  const float* src = which ? y : x;
  f16* dst = which ? hy : hx;
  const float* st = stats + which * (B_ * 32 * 2);
  int hw = threadIdx.x & 31;
  int c0 = (threadIdx.x >> 5) * 32;
  uint4 ob[4];
  f16* buf = (f16*)ob;
#pragma unroll
  for (int cc = 0; cc < 32; ++cc) {
    int c = c0 + cc;
    int g = c >> 3;
    float mean = st[(b * 32 + g) * 2 + 0];
    float rstd = st[(b * 32 + g) * 2 + 1];
    float v = src[((size_t)b * C_ + c) * HW_ + hw0 + hw];
    v = (v - mean) * rstd * gsc[c] + gbi[c];
    buf[cc] = (f16)v;
  }
  uint4* o4 = (uint4*)(dst + ((size_t)b * HW_ + hw0 + hw) * C_ + c0);
  o4[0] = ob[0]; o4[1] = ob[1]; o4[2] = ob[2]; o4[3] = ob[3];
}

// ------- fp32 -> f16 weight conversion; Wp pre-scaled by 2^16 -------
__global__ void w2h(const float* __restrict__ wq, const float* __restrict__ wk,
                    const float* __restrict__ wv, const float* __restrict__ wp,
                    f16* __restrict__ o) {
  int i = blockIdx.x * 256 + threadIdx.x;  // [0, 4*65536)
  int m = i >> 16, r = i & 65535;
  float v = (m == 0) ? wq[r] : (m == 1) ? wk[r] : (m == 2) ? wv[r] : wp[r] * WP_S;
  o[i] = (f16)v;
}

// ---- f16 MFMA GEMM: C[M][N] = A[M][256] . Bp[N][256]^T (+bias, *alpha) ----
// Full-K LDS panels (A,B: 64x256 f16, staged once, 1 barrier). 4 waves.
// OUT=1: f16 out, v = (acc + bias)*alpha   (q/k/v)
// OUT=0: fp32 out, v = acc*alpha + bias    (projection: alpha=2^-16 undoes WP_S)
template<int BIASM, int OUT>
__global__ __launch_bounds__(256, 2) void gemmh(
    const f16* __restrict__ A, const f16* __restrict__ Bp,
    const float* __restrict__ bias, void* __restrict__ Cout,
    int N, float alpha, long sA, long sB, long sC) {
  __shared__ f16 at[64][264];
  __shared__ f16 bt[64][264];
  int z = blockIdx.z;
  const f16* Ab = A + (size_t)z * sA;
  const f16* Bb = Bp + (size_t)z * sB;
  int bm = blockIdx.x * 64, bn = blockIdx.y * 64;
  int t = threadIdx.x;
  int lane = t & 63, wv = t >> 6, l15 = lane & 15, koff = (lane >> 4) * 8;
  {
    int row = t >> 2, c0 = (t & 3) * 64;    // 4 thr/row x 128B
    const uint4* pa = (const uint4*)(Ab + (size_t)(bm + row) * 256 + c0);
    const uint4* pb = (const uint4*)(Bb + (size_t)(bn + row) * 256 + c0);
    uint4* da = (uint4*)&at[row][c0];
    uint4* db = (uint4*)&bt[row][c0];
#pragma unroll
    for (int u = 0; u < 8; ++u) da[u] = pa[u];
#pragma unroll
    for (int u = 0; u < 8; ++u) db[u] = pb[u];
  }
  __syncthreads();
  floatx4 acc[4];
#pragma unroll
  for (int nt = 0; nt < 4; ++nt) acc[nt] = (floatx4){0.f, 0.f, 0.f, 0.f};
#pragma unroll
  for (int kk = 0; kk < 256; kk += 32) {
    half8 a = *(const half8*)&at[wv * 16 + l15][kk + koff];
#pragma unroll
    for (int nt = 0; nt < 4; ++nt) {
      half8 b = *(const half8*)&bt[nt * 16 + l15][kk + koff];
      acc[nt] = mfma16(a, b, acc[nt]);
    }
  }
#pragma unroll
  for (int nt = 0; nt < 4; ++nt) {
    int n = bn + nt * 16 + l15;
#pragma unroll
    for (int r = 0; r < 4; ++r) {
      int m = bm + wv * 16 + (lane >> 4) * 4 + r;
      float bv = bias[BIASM ? m : n];
      size_t idx = (size_t)z * sC + (size_t)m * N + n;
      if (OUT == 0) ((float*)Cout)[idx] = acc[nt][r] * alpha + bv;
      else          ((f16*)Cout)[idx] = (f16)((acc[nt][r] + bv) * alpha);
    }
  }
}

// -------- single-fp16 MFMA flash attention, fp32 softmax/accum, f16 out --------
__global__ __launch_bounds__(512, 1) void flashf(
    const f16* __restrict__ Q, const f16* __restrict__ K,
    const f16* __restrict__ V, f16* __restrict__ Hh) {
  int flat = blockIdx.x;            // [0, 256)
  int b = flat & 7;                 // XCD swizzle
  int m0 = (flat >> 3) * 128;
  int t = threadIdx.x;
  int lane = t & 63;
  int wv = t >> 6;
  int l15 = lane & 15;
  int koff = (lane >> 4) * 8;
  const f16* Qb = Q + (size_t)b * HW_ * C_;
  const f16* Kb = K + (size_t)b * HW_ * C_;
  const f16* Vb = V + (size_t)b * C_ * HW_;

  __shared__ f16 ks[2][32][264];
  __shared__ f16 vs[2][256][40];
  __shared__ f16 ps[8][16][40];

  int mrow = m0 + wv * 16 + l15;
  half8 qf[8];
#pragma unroll
  for (int kk = 0; kk < 8; ++kk)
    qf[kk] = *(const half8*)(Qb + (size_t)mrow * C_ + kk * 32 + koff);

  floatx4 o[16];
#pragma unroll
  for (int i = 0; i < 16; ++i) o[i] = (floatx4){0.f, 0.f, 0.f, 0.f};
  floatx4 osum = (floatx4){0.f, 0.f, 0.f, 0.f};
  float m_run[4] = {-1e30f, -1e30f, -1e30f, -1e30f};

  int krow = t >> 4, kch = (t & 15) * 16;
  int vrow = t >> 1, vch = (t & 1) * 16;
  uint4 rk0, rk1, rv0, rv1;

#define LOADT(N0)                                                            \
  {                                                                          \
    const uint4* pk = (const uint4*)(Kb + (size_t)((N0) + krow) * C_ + kch); \
    rk0 = pk[0]; rk1 = pk[1];                                                \
    const uint4* pv = (const uint4*)(Vb + (size_t)vrow * HW_ + (N0) + vch);  \
    rv0 = pv[0]; rv1 = pv[1];                                                \
  }
#define STORET(BUF)                                                          \
  {                                                                          \
    uint4* dk = (uint4*)&ks[BUF][krow][kch];                                 \
    dk[0] = rk0; dk[1] = rk1;                                                \
    uint4* dv = (uint4*)&vs[BUF][vrow][vch];                                 \
    dv[0] = rv0; dv[1] = rv1;                                                \
  }

  LOADT(0);
  STORET(0);
  LOADT(KVB);
  __syncthreads();

  const half8 ones = {(f16)1, (f16)1, (f16)1, (f16)1,
                      (f16)1, (f16)1, (f16)1, (f16)1};

  int cur = 0;
  for (int n0 = 0; n0 < HW_; n0 += KVB) {
    floatx4 s0 = {0.f, 0.f, 0.f, 0.f};
    floatx4 s1 = {0.f, 0.f, 0.f, 0.f};
    __builtin_amdgcn_s_setprio(1);
#pragma unroll
    for (int kk = 0; kk < 8; ++kk) {
      half8 k0 = *(const half8*)&ks[cur][l15][kk * 32 + koff];
      half8 k1 = *(const half8*)&ks[cur][16 + l15][kk * 32 + koff];
      s0 = mfma16(qf[kk], k0, s0);
      s1 = mfma16(qf[kk], k1, s1);
    }
    __builtin_amdgcn_s_setprio(0);

    int trig = 0;
#pragma unroll
    for (int r = 0; r < 4; ++r) {
      float thr = m_run[r] + DEFER_THR;
      trig |= (s0[r] > thr) | (s1[r] > thr);
    }
    if (__any(trig)) {
      float sc[4];
#pragma unroll
      for (int r = 0; r < 4; ++r) {
        float tm = fmaxf(s0[r], s1[r]);
        tm = fmaxf(tm, __shfl_xor(tm, 1));
        tm = fmaxf(tm, __shfl_xor(tm, 2));
        tm = fmaxf(tm, __shfl_xor(tm, 4));
        tm = fmaxf(tm, __shfl_xor(tm, 8));
        float mn = fmaxf(m_run[r], tm);
        sc[r] = __expf(m_run[r] - mn);
        m_run[r] = mn;
      }
      osum[0] *= sc[0]; osum[1] *= sc[1]; osum[2] *= sc[2]; osum[3] *= sc[3];
#pragma unroll
      for (int i = 0; i < 16; ++i) {
        o[i][0] *= sc[0]; o[i][1] *= sc[1]; o[i][2] *= sc[2]; o[i][3] *= sc[3];
      }
    }
#pragma unroll
    for (int r = 0; r < 4; ++r) {
      float p0 = __expf(s0[r] - m_run[r]);
      float p1 = __expf(s1[r] - m_run[r]);
      int mr = (lane >> 4) * 4 + r;
      ps[wv][mr][l15] = (f16)p0;
      ps[wv][mr][16 + l15] = (f16)p1;
    }
    asm volatile("s_waitcnt lgkmcnt(0)" ::: "memory");
    __builtin_amdgcn_sched_barrier(0);
    half8 pf = *(const half8*)&ps[wv][l15][koff];
    __builtin_amdgcn_s_setprio(1);
#pragma unroll
    for (int ct = 0; ct < 16; ++ct) {
      half8 vf = *(const half8*)&vs[cur][ct * 16 + l15][koff];
      o[ct] = mfma16(pf, vf, o[ct]);
    }
    osum = mfma16(pf, ones, osum);
    __builtin_amdgcn_s_setprio(0);

    bool h1 = n0 + KVB < HW_;
    bool h2 = n0 + 2 * KVB < HW_;
    if (h1) STORET(cur ^ 1);
    if (h2) LOADT(n0 + 2 * KVB);
    __syncthreads();
    cur ^= 1;
  }

  float inv[4];
#pragma unroll
  for (int r = 0; r < 4; ++r) inv[r] = 1.f / osum[r];
#pragma unroll
  for (int ct = 0; ct < 16; ++ct) {
#pragma unroll
    for (int r = 0; r < 4; ++r) {
      int m = m0 + wv * 16 + (lane >> 4) * 4 + r;
      Hh[((size_t)b * HW_ + m) * C_ + ct * 16 + l15] = (f16)(o[ct][r] * inv[r]);
    }
  }
#undef LOADT
#undef STORET
}

extern "C" void kernel_launch(void* const* d_in, const int* in_sizes, int n_in,
                              void* d_out, int out_size, void* d_ws, size_t ws_size,
                              hipStream_t stream) {
  const float* x   = (const float*)d_in[0];
  const float* tg  = (const float*)d_in[1];
  const float* gsc = (const float*)d_in[2];
  const float* gbi = (const float*)d_in[3];
  const float* Wq  = (const float*)d_in[4];
  const float* bq  = (const float*)d_in[5];
  const float* Wk  = (const float*)d_in[6];
  const float* bk  = (const float*)d_in[7];
  const float* Wv  = (const float*)d_in[8];
  const float* bv  = (const float*)d_in[9];
  const float* Wp  = (const float*)d_in[10];
  const float* bp  = (const float*)d_in[11];

  char* ws = (char*)d_ws;
  size_t off = 0;
  auto alloc = [&](size_t bytes) {
    char* p = ws + off;
    off += (bytes + 255) & ~(size_t)255;
    return p;
  };
  const size_t HSZ = (size_t)B_ * HW_ * C_ * sizeof(f16);   // 16.78 MB
  f16* hx = (f16*)alloc(HSZ);
  f16* hy = (f16*)alloc(HSZ);
  f16* qh = (f16*)alloc(HSZ);
  f16* kh = (f16*)alloc(HSZ);
  f16* vh = (f16*)alloc(HSZ);
  f16* hh = (f16*)alloc(HSZ);
  f16* w16 = (f16*)alloc((size_t)4 * 65536 * sizeof(f16));
  float* stats = (float*)alloc((size_t)2 * B_ * 32 * 2 * sizeof(float));

  gn_stats<<<dim3(512), dim3(256), 0, stream>>>(x, tg, stats);
  gn_apply<<<dim3(2048), dim3(256), 0, stream>>>(x, tg, stats, gsc, gbi, hx, hy);
  w2h<<<dim3(1024), dim3(256), 0, stream>>>(Wq, Wk, Wv, Wp, w16);
  f16* wq16 = w16;
  f16* wk16 = w16 + 65536;
  f16* wv16 = w16 + 2 * 65536;
  f16* wp16 = w16 + 3 * 65536;   // pre-scaled by 2^16

  const long sT = (long)HW_ * C_;

  // q = (hx.Wq^T + bq)*C^-0.5 -> f16 [B*HW][C]
  gemmh<0, 1><<<dim3(512, 4, 1), dim3(256), 0, stream>>>(
      hx, wq16, bq, qh, C_, 0.0625f, 0L, 0L, 0L);
  // k = hy.Wk^T + bk -> f16 [B*HW][C]
  gemmh<0, 1><<<dim3(512, 4, 1), dim3(256), 0, stream>>>(
      hy, wk16, bk, kh, C_, 1.f, 0L, 0L, 0L);
  // vT[b] = Wv.hy[b]^T + bv -> f16 [B][C][HW]
  gemmh<1, 1><<<dim3(4, 64, 8), dim3(256), 0, stream>>>(
      wv16, hy, bv, vh, HW_, 1.f, 0L, sT, (long)C_ * HW_);
  // attention
  flashf<<<dim3(256), dim3(512), 0, stream>>>(qh, kh, vh, hh);
  // out[b] = (Wp'*2^-16).h[b]^T + bp -> fp32 [B][C][HW]
  gemmh<1, 0><<<dim3(4, 64, 8), dim3(256), 0, stream>>>(
      wp16, hh, bp, d_out, HW_, WP_I, 0L, sT, (long)C_ * HW_);
}